// Round 13
// baseline (1674.939 us; speedup 1.0000x reference)
//
#include <hip/hip_runtime.h>
#include <hip/hip_bf16.h>

// Qwen2 attention layer, MI355X/gfx950.
// B=2 S=2048 HID=3584 NH=28 NKV=4 D=128, causal, GQA groups=7.
// Round 13 (= r11 attn + occupancy push): KVBLK=32 -> 32 KB LDS/block ->
// 4 blocks/CU (16 waves, was 8) to hide DS/MFMA latency (r11 was
// latency-bound: pipes sum ~40%, occupancy 9.5%). r12's 64q/wave spilled
// (reg-infeasible) and is abandoned. V rows now 64 B: swizzle key
// ((d>>1)&3)<<4 -> 2-way (free) bank spread; K swizzle unchanged.
// Sentinels: VGPR<=128, WRITE_SIZE==28672 KB.
//
// Workspace layout (bytes), total ~99.5 MB:
//   Xb    @ 0          29,360,128  (B*S x HID bf16)      -> reused as AOb after QKV GEMM
//   Wcat  @ 29,360,128 33,030,144  (4608 x 3584 bf16)    -> reused as Wo-bf16 after QKV GEMM
//   bcat  @ 62,390,272 18,432      (4608 f32)
//   QKVb  @ 62,408,704 37,748,736  (B*S x 4608 bf16)
//   Vt    @ 100,157,440 4,194,304  (B*NKV*128 x S bf16)

#define HID   3584
#define NHQ   28
#define NKVH  4
#define HD    128
#define SEQ   2048
#define NQKV  4608
#define GRP   7

typedef __attribute__((ext_vector_type(8))) short bf16x8;
typedef __attribute__((ext_vector_type(4))) float f32x4;
typedef __attribute__((ext_vector_type(16))) float f32x16;
typedef __attribute__((ext_vector_type(4))) int int4v;

#define BARRIER() asm volatile("s_barrier" ::: "memory")

__device__ __forceinline__ void gload_lds16(const void* g, void* l) {
  __builtin_amdgcn_global_load_lds(
      (const __attribute__((address_space(1))) void*)g,
      (__attribute__((address_space(3))) void*)l, 16, 0, 0);
}

__device__ __forceinline__ unsigned short f2bf(float f) {
  __hip_bfloat16 h = __float2bfloat16(f);
  return *reinterpret_cast<unsigned short*>(&h);
}

__device__ __forceinline__ float bf2f(unsigned short u) {
  __hip_bfloat16 h = *reinterpret_cast<__hip_bfloat16*>(&u);
  return __bfloat162float(h);
}

// ---------------- f32 -> bf16 conversion (vectorized, 4 elems/thread) ------
__global__ __launch_bounds__(256)
void cvt_f32_bf16(const float* __restrict__ src, __hip_bfloat16* __restrict__ dst, int n4) {
  int i = blockIdx.x * 256 + threadIdx.x;
  if (i >= n4) return;
  float4 v = ((const float4*)src)[i];
  ushort4 o;
  o.x = f2bf(v.x); o.y = f2bf(v.y); o.z = f2bf(v.z); o.w = f2bf(v.w);
  ((ushort4*)dst)[i] = o;
}

__global__ __launch_bounds__(256)
void concat_bias(const float* __restrict__ bq, const float* __restrict__ bk,
                 const float* __restrict__ bv, float* __restrict__ out) {
  int i = blockIdx.x * 256 + threadIdx.x;
  if (i < HID) out[i] = bq[i];
  else if (i < HID + 512) out[i] = bk[i - HID];
  else if (i < NQKV) out[i] = bv[i - HID - 512];
}

// ---------------- GEMM: C[M][N] = A[M][K] * B[N][K]^T (+bias) --------------
// 256x256 tile, BK=64, 8 waves, dbuf LDS, 8-phase counted-vmcnt schedule.
// 1D grid with bijective XCD swizzle (m204).
template<bool HAS_BIAS, bool OUT_BF16>
__global__ __launch_bounds__(512, 2)
void gemm256(const __hip_bfloat16* __restrict__ A, const __hip_bfloat16* __restrict__ Bm,
             const float* __restrict__ bias, void* __restrict__ Cv,
             int M, int N, int K, int nmt) {
  __shared__ __align__(16) char lds[131072];
  const int tid = threadIdx.x;
  const int w = tid >> 6, l = tid & 63;
  const int g = l >> 4, r = l & 15;
  const int wr = w >> 2, wc = w & 3;

  // bijective XCD swizzle (nwg % 8 == 0 for both our grids)
  const int nwg = gridDim.x;
  const int qq = nwg >> 3, r8 = nwg & 7;
  const int xcd = blockIdx.x & 7, idx = blockIdx.x >> 3;
  const int wgid = (xcd < r8 ? xcd * (qq + 1) : r8 * (qq + 1) + (xcd - r8) * qq) + idx;
  const int bm = (wgid % nmt) * 256, bn = (wgid / nmt) * 256;

  const int NKT = K >> 6;
  const size_t Kb2 = (size_t)K * 2;
  const int swz = (r & 7) << 4;

  auto issueHalf = [&](int kt, int h) {
    const char* src = (h < 2) ? (const char*)A : (const char*)Bm;
    const int rbase = (h < 2) ? bm : bn;
    char* reg = lds + (kt & 1) * 65536 + ((h < 2) ? 0 : 32768);
#pragma unroll
    for (int i = 0; i < 2; ++i) {
      const int lrow = (h & 1) * 128 + w * 16 + i * 8;   // wave-uniform dest row
      const int row = lrow + (l >> 3);                    // per-lane source row
      const int cb = (l & 7) * 16;
      gload_lds16(src + (size_t)(rbase + row) * Kb2 + (size_t)kt * 128 + (cb ^ ((row & 7) << 4)),
                  reg + lrow * 128);
    }
  };

  auto ldA = [&](int d, int mf, int kk) -> bf16x8 {
    const int row = wr * 128 + mf * 16 + r;
    return *(const bf16x8*)(lds + d * 65536 + row * 128 + ((kk * 64 + g * 16) ^ swz));
  };
  auto ldB = [&](int d, int nf, int kk) -> bf16x8 {
    const int row = wc * 64 + nf * 16 + r;
    return *(const bf16x8*)(lds + d * 65536 + 32768 + row * 128 + ((kk * 64 + g * 16) ^ swz));
  };

  f32x4 acc[8][4];
#pragma unroll
  for (int m = 0; m < 8; m++)
#pragma unroll
    for (int n = 0; n < 4; n++) acc[m][n] = (f32x4){0.f, 0.f, 0.f, 0.f};

#pragma unroll
  for (int h = 0; h < 4; ++h) issueHalf(0, h);
#pragma unroll
  for (int h = 0; h < 4; ++h) issueHalf(1, h);
  asm volatile("s_waitcnt vmcnt(8)" ::: "memory");
  BARRIER();

  bf16x8 af[4][2], bfr[4][2];

#pragma unroll 1
  for (int kt = 0; kt < NKT; ++kt) {
    const int d = kt & 1;

    if (kt >= 1 && kt + 1 < NKT) { issueHalf(kt + 1, 1); issueHalf(kt + 1, 3); }
#pragma unroll
    for (int mf = 0; mf < 4; mf++)
#pragma unroll
      for (int kk = 0; kk < 2; kk++) af[mf][kk] = ldA(d, mf, kk);
#pragma unroll
    for (int nf = 0; nf < 2; nf++)
#pragma unroll
      for (int kk = 0; kk < 2; kk++) bfr[nf][kk] = ldB(d, nf, kk);
    BARRIER();
    __builtin_amdgcn_s_setprio(1);
#pragma unroll
    for (int mf = 0; mf < 4; mf++)
#pragma unroll
      for (int nf = 0; nf < 2; nf++)
#pragma unroll
        for (int kk = 0; kk < 2; kk++)
          acc[mf][nf] = __builtin_amdgcn_mfma_f32_16x16x32_bf16(af[mf][kk], bfr[nf][kk], acc[mf][nf], 0, 0, 0);
    __builtin_amdgcn_s_setprio(0);
    BARRIER();

#pragma unroll
    for (int nf = 2; nf < 4; nf++)
#pragma unroll
      for (int kk = 0; kk < 2; kk++) bfr[nf][kk] = ldB(d, nf, kk);
    BARRIER();
    __builtin_amdgcn_s_setprio(1);
#pragma unroll
    for (int mf = 0; mf < 4; mf++)
#pragma unroll
      for (int nf = 2; nf < 4; nf++)
#pragma unroll
        for (int kk = 0; kk < 2; kk++)
          acc[mf][nf] = __builtin_amdgcn_mfma_f32_16x16x32_bf16(af[mf][kk], bfr[nf][kk], acc[mf][nf], 0, 0, 0);
    __builtin_amdgcn_s_setprio(0);
    BARRIER();

    if (kt + 2 < NKT) issueHalf(kt + 2, 2);
#pragma unroll
    for (int mf = 0; mf < 4; mf++)
#pragma unroll
      for (int kk = 0; kk < 2; kk++) af[mf][kk] = ldA(d, mf + 4, kk);
    BARRIER();
    __builtin_amdgcn_s_setprio(1);
#pragma unroll
    for (int mf = 0; mf < 4; mf++)
#pragma unroll
      for (int nf = 0; nf < 2; nf++)
#pragma unroll
        for (int kk = 0; kk < 2; kk++)
          acc[mf + 4][nf] = __builtin_amdgcn_mfma_f32_16x16x32_bf16(af[mf][kk], bfr[nf][kk], acc[mf + 4][nf], 0, 0, 0);
    __builtin_amdgcn_s_setprio(0);
    BARRIER();

    if (kt + 2 < NKT) {
      issueHalf(kt + 2, 0);
      asm volatile("s_waitcnt vmcnt(4)" ::: "memory");
    } else if (kt + 1 < NKT) {
      asm volatile("s_waitcnt vmcnt(0)" ::: "memory");
    }
    BARRIER();
    __builtin_amdgcn_s_setprio(1);
#pragma unroll
    for (int mf = 0; mf < 4; mf++)
#pragma unroll
      for (int nf = 2; nf < 4; nf++)
#pragma unroll
        for (int kk = 0; kk < 2; kk++)
          acc[mf + 4][nf] = __builtin_amdgcn_mfma_f32_16x16x32_bf16(af[mf][kk], bfr[nf][kk], acc[mf + 4][nf], 0, 0, 0);
    __builtin_amdgcn_s_setprio(0);
    BARRIER();
  }

#pragma unroll
  for (int nf = 0; nf < 4; nf++) {
    const int gcol = bn + wc * 64 + nf * 16 + r;
    const float bv = HAS_BIAS ? bias[gcol] : 0.f;
#pragma unroll
    for (int mf = 0; mf < 8; mf++) {
#pragma unroll
      for (int j = 0; j < 4; j++) {
        const int grow = bm + wr * 128 + mf * 16 + 4 * g + j;
        float v = acc[mf][nf][j] + bv;
        if constexpr (OUT_BF16)
          ((__hip_bfloat16*)Cv)[(size_t)grow * N + gcol] = __float2bfloat16(v);
        else
          ((float*)Cv)[(size_t)grow * N + gcol] = v;
      }
    }
  }
}

// ---------------- RoPE on Q and K head slots (in-place, bf16, x4 vec) ------
__global__ __launch_bounds__(256)
void rope_qk(__hip_bfloat16* __restrict__ QKV, const float* __restrict__ cosb,
             const float* __restrict__ sinb) {
  int i = blockIdx.x * 256 + threadIdx.x;   // 2,097,152 threads
  int d = (i & 15) * 4;
  int hh = (i >> 4) & 31;
  int row = i >> 9;
  int cb = (hh < NHQ) ? hh * HD : HID + (hh - NHQ) * HD;
  unsigned short* base = (unsigned short*)QKV + (size_t)row * NQKV + cb;
  float4 c = *(const float4*)&cosb[row * HD + d];
  float4 sn = *(const float4*)&sinb[row * HD + d];
  ushort4 u1 = *(const ushort4*)(base + d);
  ushort4 u2 = *(const ushort4*)(base + d + 64);
  float x1[4] = {bf2f(u1.x), bf2f(u1.y), bf2f(u1.z), bf2f(u1.w)};
  float x2[4] = {bf2f(u2.x), bf2f(u2.y), bf2f(u2.z), bf2f(u2.w)};
  float cc[4] = {c.x, c.y, c.z, c.w};
  float ss[4] = {sn.x, sn.y, sn.z, sn.w};
  ushort4 o1, o2;
  o1.x = f2bf(x1[0] * cc[0] - x2[0] * ss[0]); o2.x = f2bf(x2[0] * cc[0] + x1[0] * ss[0]);
  o1.y = f2bf(x1[1] * cc[1] - x2[1] * ss[1]); o2.y = f2bf(x2[1] * cc[1] + x1[1] * ss[1]);
  o1.z = f2bf(x1[2] * cc[2] - x2[2] * ss[2]); o2.z = f2bf(x2[2] * cc[2] + x1[2] * ss[2]);
  o1.w = f2bf(x1[3] * cc[3] - x2[3] * ss[3]); o2.w = f2bf(x2[3] * cc[3] + x1[3] * ss[3]);
  *(ushort4*)(base + d) = o1;
  *(ushort4*)(base + d + 64) = o2;
}

// ---------------- V transpose: Vt[b][kv][d][s] = V[b][s][kv][d] ------------
__global__ __launch_bounds__(256)
void v_transpose(const __hip_bfloat16* __restrict__ QKV, __hip_bfloat16* __restrict__ Vt) {
  int i = blockIdx.x * 256 + threadIdx.x;
  int s = i & (SEQ - 1);
  int d = (i >> 11) & (HD - 1);
  int kv = (i >> 18) & 3;
  int b = i >> 20;
  Vt[i] = QKV[(size_t)(b * SEQ + s) * NQKV + HID + 512 + kv * HD + d];
}

// ---------------- Flash attention: 32x32 MFMA, KVBLK=32, 4 blocks/CU -------
// 4 waves x 32 q-rows, 32-col KV tiles double-buffered (32 KB LDS total).
// Swapped QK^T: s = mfma_32x32(K, Q) -> lane l holds
// S^T[kv0+(j&3)+8(j>>2)+4hf][q=qw+(l&31)], hf=l>>5. Softmax per-lane +
// one shfl_xor(32). PV B-frags built transiently via permlane32_swap.
// V rows are 64 B: swizzle key ((d>>1)&3)<<4 (2-way = free).
__global__ __launch_bounds__(256, 4)
void attn_fwd(const __hip_bfloat16* __restrict__ QKV, const __hip_bfloat16* __restrict__ Vt,
              __hip_bfloat16* __restrict__ AO) {
  const int qb = 15 - blockIdx.x;           // LPT: longest blocks first
  const int head = blockIdx.y;              // 0..27
  const int b = blockIdx.z;                 // 0..1
  const int kvh = head / GRP;
  const int tid = threadIdx.x;
  const int w = tid >> 6, l = tid & 63;
  const int q32 = l & 31;                   // lane's q within wave tile
  const int hf = l >> 5;                    // lane half
  const int qw = qb * 128 + w * 32;         // wave's first q row
  const float scl2 = 0.12751744055204955f;  // (1/sqrt(128)) * log2(e)
  const float NEGINF = -__builtin_inff();

  __shared__ __align__(16) __hip_bfloat16 Ks[2][32 * 128];   // 2x8 KB, swizzled
  __shared__ __align__(16) __hip_bfloat16 Vs[2][128 * 32];   // 2x8 KB, swizzled

  const char* Kb = (const char*)(QKV + (size_t)(b * SEQ) * NQKV + HID + kvh * HD);
  const char* Vb = (const char*)(Vt + (size_t)((b * NKVH + kvh) * HD) * SEQ);
  const __hip_bfloat16* Qb = QKV + (size_t)(b * SEQ + qw) * NQKV + head * HD;

  // Q fragments (B-operand, 32x32x16): qf[c] = Q[qw+q32][16c + 8hf + 0..7]
  bf16x8 qf[8];
#pragma unroll
  for (int c = 0; c < 8; c++)
    qf[c] = *(const bf16x8*)&Qb[(size_t)q32 * NQKV + c * 16 + 8 * hf];

  f32x16 of[4] = {};
  float mrow = -3e38f, lsum = 0.f;

  const int ntiles = 4 * qb + 4;

  auto stage = [&](int buf, int kv0) {
#pragma unroll
    for (int p = 0; p < 2; p++) {
      const int row = w * 8 + p * 4 + (l >> 4);       // K tile row (0..31)
      const int cb = (l & 15) * 16;
      gload_lds16(Kb + (size_t)(kv0 + row) * (NQKV * 2) + (cb ^ ((row & 7) << 4)),
                  (char*)(Ks[buf]) + w * 2048 + p * 1024);
    }
#pragma unroll
    for (int p = 0; p < 2; p++) {
      const int row = w * 32 + p * 16 + (l >> 2);     // V^T tile row (= d, 0..127)
      const int cb = (l & 3) * 16;
      gload_lds16(Vb + (size_t)row * (SEQ * 2) + (size_t)kv0 * 2 + (cb ^ (((row >> 1) & 3) << 4)),
                  (char*)(Vs[buf]) + w * 2048 + p * 1024);
    }
  };

  stage(0, 0);
  __syncthreads();

  const int swz = (q32 & 7) << 4;        // K-read swizzle (256 B rows)
  const int vswz = ((q32 >> 1) & 3) << 4; // V-read swizzle (64 B rows), lane-const
  const int qg = qw + q32;

  for (int t = 0; t < ntiles; t++) {
    const int kv0 = t * 32;
    const int cur = t & 1;
    if (t + 1 < ntiles) stage(cur ^ 1, kv0 + 32);    // prefetch under compute

    if (kv0 <= qw + 31) {
      // ---- QK^T swapped, 32x32x16 (one 32-col tile)
      f32x16 s = {};
      const char* kb = (const char*)(Ks[cur]) + q32 * 256;
#pragma unroll
      for (int c = 0; c < 8; c++) {
        bf16x8 kf = *(const bf16x8*)(kb + ((c * 32 + 16 * hf) ^ swz));
        s = __builtin_amdgcn_mfma_f32_32x32x16_bf16(kf, qf[c], s, 0, 0, 0);
      }

      // ---- mask + scale + per-lane max
      float pmax = -3e38f;
      if (kv0 + 31 <= qw) {               // interior tile: no mask
#pragma unroll
        for (int j = 0; j < 16; j++) { s[j] *= scl2; pmax = fmaxf(pmax, s[j]); }
      } else {
#pragma unroll
        for (int j = 0; j < 16; j++) {
          const int kvl = (j & 3) + 8 * (j >> 2) + 4 * hf;
          s[j] = (kv0 + kvl <= qg) ? s[j] * scl2 : NEGINF;
          pmax = fmaxf(pmax, s[j]);
        }
      }
      pmax = fmaxf(pmax, __shfl_xor(pmax, 32));

      // ---- online softmax, defer-max (THR=11.5 in log2 domain)
      float rs = 0.f;
      if (__all(pmax - mrow <= 11.5f)) {
#pragma unroll
        for (int j = 0; j < 16; j++) { float p = exp2f(s[j] - mrow); s[j] = p; rs += p; }
      } else {
        const float nm = fmaxf(mrow, pmax);
        const float al = exp2f(mrow - nm);
        mrow = nm;
#pragma unroll
        for (int j = 0; j < 16; j++) { float p = exp2f(s[j] - nm); s[j] = p; rs += p; }
        lsum *= al;
#pragma unroll
        for (int db = 0; db < 4; db++) of[db] *= al;
      }
      rs += __shfl_xor(rs, 32);
      lsum += rs;

      // ---- pack P pairs -> u32 words (8 live)
      int wv[8];
#pragma unroll
      for (int k = 0; k < 8; k++)
        wv[k] = (int)((unsigned)f2bf(s[2 * k]) | ((unsigned)f2bf(s[2 * k + 1]) << 16));

      // ---- PV t4=0: pB built transiently; kv local 0..15
      {
        auto ra = __builtin_amdgcn_permlane32_swap(wv[0], wv[2], false, false);
        auto rb = __builtin_amdgcn_permlane32_swap(wv[1], wv[3], false, false);
        union { int4v i; bf16x8 h; } u;
        u.i = (int4v){(int)ra[0], (int)rb[0], (int)ra[1], (int)rb[1]};
        const bf16x8 pB = u.h;
#pragma unroll
        for (int db = 0; db < 4; db++) {
          const char* vp = (const char*)(Vs[cur]) + (db * 32 + q32) * 64;
          bf16x8 vf = *(const bf16x8*)(vp + ((0 * 32 + 16 * hf) ^ vswz));
          of[db] = __builtin_amdgcn_mfma_f32_32x32x16_bf16(vf, pB, of[db], 0, 0, 0);
        }
      }
      // ---- PV t4=1: kv local 16..31
      {
        auto rc = __builtin_amdgcn_permlane32_swap(wv[4], wv[6], false, false);
        auto rd = __builtin_amdgcn_permlane32_swap(wv[5], wv[7], false, false);
        union { int4v i; bf16x8 h; } u2;
        u2.i = (int4v){(int)rc[0], (int)rd[0], (int)rc[1], (int)rd[1]};
        const bf16x8 pB = u2.h;
#pragma unroll
        for (int db = 0; db < 4; db++) {
          const char* vp = (const char*)(Vs[cur]) + (db * 32 + q32) * 64;
          bf16x8 vf = *(const bf16x8*)(vp + ((1 * 32 + 16 * hf) ^ vswz));
          of[db] = __builtin_amdgcn_mfma_f32_32x32x16_bf16(vf, pB, of[db], 0, 0, 0);
        }
      }
    }
    __syncthreads();   // drains prefetch + guards buffer reuse
  }

  // ---- epilogue: of[db] reg j -> d = 32db + 8(j>>2) + 4hf + (j&3), q = qw+q32
  unsigned short* AOu = (unsigned short*)AO;
  const float inv = 1.0f / lsum;
  const size_t rowb = (size_t)(b * SEQ + qw + q32) * HID + head * HD;
#pragma unroll
  for (int db = 0; db < 4; db++) {
#pragma unroll
    for (int qd = 0; qd < 4; qd++) {
      ushort4 o;
      o.x = f2bf(of[db][4 * qd + 0] * inv);
      o.y = f2bf(of[db][4 * qd + 1] * inv);
      o.z = f2bf(of[db][4 * qd + 2] * inv);
      o.w = f2bf(of[db][4 * qd + 3] * inv);
      *(ushort4*)&AOu[rowb + db * 32 + 8 * qd + 4 * hf] = o;
    }
  }
}

// ---------------------------------------------------------------------------
extern "C" void kernel_launch(void* const* d_in, const int* in_sizes, int n_in,
                              void* d_out, int out_size, void* d_ws, size_t ws_size,
                              hipStream_t stream) {
  const float* hs = (const float*)d_in[0];
  const float* cosb = (const float*)d_in[1];
  const float* sinb = (const float*)d_in[2];
  const float* Wq = (const float*)d_in[3];
  const float* bq = (const float*)d_in[4];
  const float* Wk = (const float*)d_in[5];
  const float* bk = (const float*)d_in[6];
  const float* Wv = (const float*)d_in[7];
  const float* bv = (const float*)d_in[8];
  const float* Wo = (const float*)d_in[9];

  char* ws = (char*)d_ws;
  __hip_bfloat16* Xb = (__hip_bfloat16*)(ws);
  __hip_bfloat16* Wcat = (__hip_bfloat16*)(ws + 29360128);
  float* bcat = (float*)(ws + 62390272);
  __hip_bfloat16* QKVb = (__hip_bfloat16*)(ws + 62408704);
  __hip_bfloat16* Vt = (__hip_bfloat16*)(ws + 100157440);
  __hip_bfloat16* AOb = Xb;    // X dead after QKV GEMM
  __hip_bfloat16* Wob = Wcat;  // Wcat dead after QKV GEMM

  // Conversions to bf16
  cvt_f32_bf16<<<14336, 256, 0, stream>>>(hs, Xb, 3670016);                       // X
  cvt_f32_bf16<<<12544, 256, 0, stream>>>(Wq, Wcat, 3211264);                     // Wq rows 0..3583
  cvt_f32_bf16<<<1792, 256, 0, stream>>>(Wk, Wcat + (size_t)3584 * 3584, 458752); // Wk rows 3584..4095
  cvt_f32_bf16<<<1792, 256, 0, stream>>>(Wv, Wcat + (size_t)4096 * 3584, 458752); // Wv rows 4096..4607
  concat_bias<<<18, 256, 0, stream>>>(bq, bk, bv, bcat);

  // Fused QKV projection: [4096 x 3584] @ [4608 x 3584]^T + bias -> bf16
  gemm256<true, true><<<288, 512, 0, stream>>>(Xb, Wcat, bcat, QKVb, 4096, NQKV, HID, 16);

  // RoPE on Q + K head slots (in place, vectorized x4)
  rope_qk<<<8192, 256, 0, stream>>>(QKVb, cosb, sinb);

  // V transpose for PV fragment loads
  v_transpose<<<8192, 256, 0, stream>>>(QKVb, Vt);

  // Wo conversion (into the now-dead Wcat region)
  cvt_f32_bf16<<<12544, 256, 0, stream>>>(Wo, Wob, 3211264);

  // Flash attention: 128-row Q blocks, 4 waves x 32 rows, 32-col KV tiles
  dim3 ga(16, NHQ, 2);
  attn_fwd<<<ga, 256, 0, stream>>>(QKVb, Vt, AOb);

  // O projection -> f32 out
  gemm256<false, false><<<224, 512, 0, stream>>>(AOb, Wob, nullptr, d_out, 4096, HID, HID, 16);
}

// Round 14
// 493.516 us; speedup vs baseline: 3.3939x; 3.3939x over previous
//
#include <hip/hip_runtime.h>
#include <hip/hip_bf16.h>

// Qwen2 attention layer, MI355X/gfx950.
// B=2 S=2048 HID=3584 NH=28 NKV=4 D=128, causal, GQA groups=7.
// Round 14 = round 11 (proven best: 587 us) + correct LPT dispatch order.
// r12 (64q/wave) and r13 (4 blocks/CU) both spilled: this attn structure
// needs ~188 unified regs -> 2 waves/SIMD is the feasible optimum.
// Grid now (head*2+b, qbIdx) with qb SLOWEST-varying so all 56 heaviest
// (qb=15) blocks dispatch first (x-fastest linear dispatch).
//
// Workspace layout (bytes), total ~99.5 MB:
//   Xb    @ 0          29,360,128  (B*S x HID bf16)      -> reused as AOb after QKV GEMM
//   Wcat  @ 29,360,128 33,030,144  (4608 x 3584 bf16)    -> reused as Wo-bf16 after QKV GEMM
//   bcat  @ 62,390,272 18,432      (4608 f32)
//   QKVb  @ 62,408,704 37,748,736  (B*S x 4608 bf16)
//   Vt    @ 100,157,440 4,194,304  (B*NKV*128 x S bf16)

#define HID   3584
#define NHQ   28
#define NKVH  4
#define HD    128
#define SEQ   2048
#define NQKV  4608
#define GRP   7

typedef __attribute__((ext_vector_type(8))) short bf16x8;
typedef __attribute__((ext_vector_type(4))) float f32x4;
typedef __attribute__((ext_vector_type(16))) float f32x16;
typedef __attribute__((ext_vector_type(4))) int int4v;

#define BARRIER() asm volatile("s_barrier" ::: "memory")

__device__ __forceinline__ void gload_lds16(const void* g, void* l) {
  __builtin_amdgcn_global_load_lds(
      (const __attribute__((address_space(1))) void*)g,
      (__attribute__((address_space(3))) void*)l, 16, 0, 0);
}

__device__ __forceinline__ unsigned short f2bf(float f) {
  __hip_bfloat16 h = __float2bfloat16(f);
  return *reinterpret_cast<unsigned short*>(&h);
}

__device__ __forceinline__ float bf2f(unsigned short u) {
  __hip_bfloat16 h = *reinterpret_cast<__hip_bfloat16*>(&u);
  return __bfloat162float(h);
}

// ---------------- f32 -> bf16 conversion (vectorized, 4 elems/thread) ------
__global__ __launch_bounds__(256)
void cvt_f32_bf16(const float* __restrict__ src, __hip_bfloat16* __restrict__ dst, int n4) {
  int i = blockIdx.x * 256 + threadIdx.x;
  if (i >= n4) return;
  float4 v = ((const float4*)src)[i];
  ushort4 o;
  o.x = f2bf(v.x); o.y = f2bf(v.y); o.z = f2bf(v.z); o.w = f2bf(v.w);
  ((ushort4*)dst)[i] = o;
}

__global__ __launch_bounds__(256)
void concat_bias(const float* __restrict__ bq, const float* __restrict__ bk,
                 const float* __restrict__ bv, float* __restrict__ out) {
  int i = blockIdx.x * 256 + threadIdx.x;
  if (i < HID) out[i] = bq[i];
  else if (i < HID + 512) out[i] = bk[i - HID];
  else if (i < NQKV) out[i] = bv[i - HID - 512];
}

// ---------------- GEMM: C[M][N] = A[M][K] * B[N][K]^T (+bias) --------------
// 256x256 tile, BK=64, 8 waves, dbuf LDS, 8-phase counted-vmcnt schedule.
// 1D grid with bijective XCD swizzle (m204).
template<bool HAS_BIAS, bool OUT_BF16>
__global__ __launch_bounds__(512, 2)
void gemm256(const __hip_bfloat16* __restrict__ A, const __hip_bfloat16* __restrict__ Bm,
             const float* __restrict__ bias, void* __restrict__ Cv,
             int M, int N, int K, int nmt) {
  __shared__ __align__(16) char lds[131072];
  const int tid = threadIdx.x;
  const int w = tid >> 6, l = tid & 63;
  const int g = l >> 4, r = l & 15;
  const int wr = w >> 2, wc = w & 3;

  // bijective XCD swizzle (nwg % 8 == 0 for both our grids)
  const int nwg = gridDim.x;
  const int qq = nwg >> 3, r8 = nwg & 7;
  const int xcd = blockIdx.x & 7, idx = blockIdx.x >> 3;
  const int wgid = (xcd < r8 ? xcd * (qq + 1) : r8 * (qq + 1) + (xcd - r8) * qq) + idx;
  const int bm = (wgid % nmt) * 256, bn = (wgid / nmt) * 256;

  const int NKT = K >> 6;
  const size_t Kb2 = (size_t)K * 2;
  const int swz = (r & 7) << 4;

  auto issueHalf = [&](int kt, int h) {
    const char* src = (h < 2) ? (const char*)A : (const char*)Bm;
    const int rbase = (h < 2) ? bm : bn;
    char* reg = lds + (kt & 1) * 65536 + ((h < 2) ? 0 : 32768);
#pragma unroll
    for (int i = 0; i < 2; ++i) {
      const int lrow = (h & 1) * 128 + w * 16 + i * 8;   // wave-uniform dest row
      const int row = lrow + (l >> 3);                    // per-lane source row
      const int cb = (l & 7) * 16;
      gload_lds16(src + (size_t)(rbase + row) * Kb2 + (size_t)kt * 128 + (cb ^ ((row & 7) << 4)),
                  reg + lrow * 128);
    }
  };

  auto ldA = [&](int d, int mf, int kk) -> bf16x8 {
    const int row = wr * 128 + mf * 16 + r;
    return *(const bf16x8*)(lds + d * 65536 + row * 128 + ((kk * 64 + g * 16) ^ swz));
  };
  auto ldB = [&](int d, int nf, int kk) -> bf16x8 {
    const int row = wc * 64 + nf * 16 + r;
    return *(const bf16x8*)(lds + d * 65536 + 32768 + row * 128 + ((kk * 64 + g * 16) ^ swz));
  };

  f32x4 acc[8][4];
#pragma unroll
  for (int m = 0; m < 8; m++)
#pragma unroll
    for (int n = 0; n < 4; n++) acc[m][n] = (f32x4){0.f, 0.f, 0.f, 0.f};

#pragma unroll
  for (int h = 0; h < 4; ++h) issueHalf(0, h);
#pragma unroll
  for (int h = 0; h < 4; ++h) issueHalf(1, h);
  asm volatile("s_waitcnt vmcnt(8)" ::: "memory");
  BARRIER();

  bf16x8 af[4][2], bfr[4][2];

#pragma unroll 1
  for (int kt = 0; kt < NKT; ++kt) {
    const int d = kt & 1;

    if (kt >= 1 && kt + 1 < NKT) { issueHalf(kt + 1, 1); issueHalf(kt + 1, 3); }
#pragma unroll
    for (int mf = 0; mf < 4; mf++)
#pragma unroll
      for (int kk = 0; kk < 2; kk++) af[mf][kk] = ldA(d, mf, kk);
#pragma unroll
    for (int nf = 0; nf < 2; nf++)
#pragma unroll
      for (int kk = 0; kk < 2; kk++) bfr[nf][kk] = ldB(d, nf, kk);
    BARRIER();
    __builtin_amdgcn_s_setprio(1);
#pragma unroll
    for (int mf = 0; mf < 4; mf++)
#pragma unroll
      for (int nf = 0; nf < 2; nf++)
#pragma unroll
        for (int kk = 0; kk < 2; kk++)
          acc[mf][nf] = __builtin_amdgcn_mfma_f32_16x16x32_bf16(af[mf][kk], bfr[nf][kk], acc[mf][nf], 0, 0, 0);
    __builtin_amdgcn_s_setprio(0);
    BARRIER();

#pragma unroll
    for (int nf = 2; nf < 4; nf++)
#pragma unroll
      for (int kk = 0; kk < 2; kk++) bfr[nf][kk] = ldB(d, nf, kk);
    BARRIER();
    __builtin_amdgcn_s_setprio(1);
#pragma unroll
    for (int mf = 0; mf < 4; mf++)
#pragma unroll
      for (int nf = 2; nf < 4; nf++)
#pragma unroll
        for (int kk = 0; kk < 2; kk++)
          acc[mf][nf] = __builtin_amdgcn_mfma_f32_16x16x32_bf16(af[mf][kk], bfr[nf][kk], acc[mf][nf], 0, 0, 0);
    __builtin_amdgcn_s_setprio(0);
    BARRIER();

    if (kt + 2 < NKT) issueHalf(kt + 2, 2);
#pragma unroll
    for (int mf = 0; mf < 4; mf++)
#pragma unroll
      for (int kk = 0; kk < 2; kk++) af[mf][kk] = ldA(d, mf + 4, kk);
    BARRIER();
    __builtin_amdgcn_s_setprio(1);
#pragma unroll
    for (int mf = 0; mf < 4; mf++)
#pragma unroll
      for (int nf = 0; nf < 2; nf++)
#pragma unroll
        for (int kk = 0; kk < 2; kk++)
          acc[mf + 4][nf] = __builtin_amdgcn_mfma_f32_16x16x32_bf16(af[mf][kk], bfr[nf][kk], acc[mf + 4][nf], 0, 0, 0);
    __builtin_amdgcn_s_setprio(0);
    BARRIER();

    if (kt + 2 < NKT) {
      issueHalf(kt + 2, 0);
      asm volatile("s_waitcnt vmcnt(4)" ::: "memory");
    } else if (kt + 1 < NKT) {
      asm volatile("s_waitcnt vmcnt(0)" ::: "memory");
    }
    BARRIER();
    __builtin_amdgcn_s_setprio(1);
#pragma unroll
    for (int mf = 0; mf < 4; mf++)
#pragma unroll
      for (int nf = 2; nf < 4; nf++)
#pragma unroll
        for (int kk = 0; kk < 2; kk++)
          acc[mf + 4][nf] = __builtin_amdgcn_mfma_f32_16x16x32_bf16(af[mf][kk], bfr[nf][kk], acc[mf + 4][nf], 0, 0, 0);
    __builtin_amdgcn_s_setprio(0);
    BARRIER();
  }

#pragma unroll
  for (int nf = 0; nf < 4; nf++) {
    const int gcol = bn + wc * 64 + nf * 16 + r;
    const float bv = HAS_BIAS ? bias[gcol] : 0.f;
#pragma unroll
    for (int mf = 0; mf < 8; mf++) {
#pragma unroll
      for (int j = 0; j < 4; j++) {
        const int grow = bm + wr * 128 + mf * 16 + 4 * g + j;
        float v = acc[mf][nf][j] + bv;
        if constexpr (OUT_BF16)
          ((__hip_bfloat16*)Cv)[(size_t)grow * N + gcol] = __float2bfloat16(v);
        else
          ((float*)Cv)[(size_t)grow * N + gcol] = v;
      }
    }
  }
}

// ---------------- RoPE on Q and K head slots (in-place, bf16, x4 vec) ------
__global__ __launch_bounds__(256)
void rope_qk(__hip_bfloat16* __restrict__ QKV, const float* __restrict__ cosb,
             const float* __restrict__ sinb) {
  int i = blockIdx.x * 256 + threadIdx.x;   // 2,097,152 threads
  int d = (i & 15) * 4;
  int hh = (i >> 4) & 31;
  int row = i >> 9;
  int cb = (hh < NHQ) ? hh * HD : HID + (hh - NHQ) * HD;
  unsigned short* base = (unsigned short*)QKV + (size_t)row * NQKV + cb;
  float4 c = *(const float4*)&cosb[row * HD + d];
  float4 sn = *(const float4*)&sinb[row * HD + d];
  ushort4 u1 = *(const ushort4*)(base + d);
  ushort4 u2 = *(const ushort4*)(base + d + 64);
  float x1[4] = {bf2f(u1.x), bf2f(u1.y), bf2f(u1.z), bf2f(u1.w)};
  float x2[4] = {bf2f(u2.x), bf2f(u2.y), bf2f(u2.z), bf2f(u2.w)};
  float cc[4] = {c.x, c.y, c.z, c.w};
  float ss[4] = {sn.x, sn.y, sn.z, sn.w};
  ushort4 o1, o2;
  o1.x = f2bf(x1[0] * cc[0] - x2[0] * ss[0]); o2.x = f2bf(x2[0] * cc[0] + x1[0] * ss[0]);
  o1.y = f2bf(x1[1] * cc[1] - x2[1] * ss[1]); o2.y = f2bf(x2[1] * cc[1] + x1[1] * ss[1]);
  o1.z = f2bf(x1[2] * cc[2] - x2[2] * ss[2]); o2.z = f2bf(x2[2] * cc[2] + x1[2] * ss[2]);
  o1.w = f2bf(x1[3] * cc[3] - x2[3] * ss[3]); o2.w = f2bf(x2[3] * cc[3] + x1[3] * ss[3]);
  *(ushort4*)(base + d) = o1;
  *(ushort4*)(base + d + 64) = o2;
}

// ---------------- V transpose: Vt[b][kv][d][s] = V[b][s][kv][d] ------------
__global__ __launch_bounds__(256)
void v_transpose(const __hip_bfloat16* __restrict__ QKV, __hip_bfloat16* __restrict__ Vt) {
  int i = blockIdx.x * 256 + threadIdx.x;
  int s = i & (SEQ - 1);
  int d = (i >> 11) & (HD - 1);
  int kv = (i >> 18) & 3;
  int b = i >> 20;
  Vt[i] = QKV[(size_t)(b * SEQ + s) * NQKV + HID + 512 + kv * HD + d];
}

// ---------------- Flash attention: 32x32 MFMA, streaming 32-col passes -----
// (r11 structure, proven 231 us / zero spill.) 4 waves x 32 q-rows,
// KVBLK=64 staged dbuf, compute in two 32-col passes: one f32x16 S-tile +
// one wv[8] live at a time, pB built transiently via permlane32_swap.
// Grid: x = head*2+b (fast), y = qb index (slow) -> heavy blocks first.
__global__ __launch_bounds__(256, 2)
void attn_fwd(const __hip_bfloat16* __restrict__ QKV, const __hip_bfloat16* __restrict__ Vt,
              __hip_bfloat16* __restrict__ AO) {
  const int head = blockIdx.x >> 1;         // 0..27
  const int b = blockIdx.x & 1;             // 0..1
  const int qb = 15 - blockIdx.y;           // LPT: qb=15 blocks dispatch first
  const int kvh = head / GRP;
  const int tid = threadIdx.x;
  const int w = tid >> 6, l = tid & 63;
  const int q32 = l & 31;                   // lane's q within wave tile
  const int hf = l >> 5;                    // lane half
  const int qw = qb * 128 + w * 32;         // wave's first q row
  const float scl2 = 0.12751744055204955f;  // (1/sqrt(128)) * log2(e)
  const float NEGINF = -__builtin_inff();

  __shared__ __align__(16) __hip_bfloat16 Ks[2][64 * 128];   // 2x16 KB, swizzled
  __shared__ __align__(16) __hip_bfloat16 Vs[2][128 * 64];   // 2x16 KB, swizzled

  const char* Kb = (const char*)(QKV + (size_t)(b * SEQ) * NQKV + HID + kvh * HD);
  const char* Vb = (const char*)(Vt + (size_t)((b * NKVH + kvh) * HD) * SEQ);
  const __hip_bfloat16* Qb = QKV + (size_t)(b * SEQ + qw) * NQKV + head * HD;

  // Q fragments (B-operand, 32x32x16): qf[c] = Q[qw+q32][16c + 8hf + 0..7]
  bf16x8 qf[8];
#pragma unroll
  for (int c = 0; c < 8; c++)
    qf[c] = *(const bf16x8*)&Qb[(size_t)q32 * NQKV + c * 16 + 8 * hf];

  f32x16 of[4] = {};
  float mrow = -3e38f, lsum = 0.f;

  const int ntiles = 2 * qb + 2;

  auto stage = [&](int buf, int kv0) {
#pragma unroll
    for (int p = 0; p < 4; p++) {
      const int row = w * 16 + p * 4 + (l >> 4);      // K tile row (local)
      const int cb = (l & 15) * 16;
      gload_lds16(Kb + (size_t)(kv0 + row) * (NQKV * 2) + (cb ^ ((row & 7) << 4)),
                  (char*)(Ks[buf]) + w * 4096 + p * 1024);
    }
#pragma unroll
    for (int p = 0; p < 4; p++) {
      const int row = w * 32 + p * 8 + (l >> 3);      // V^T tile row (= d)
      const int cb = (l & 7) * 16;
      gload_lds16(Vb + (size_t)row * (SEQ * 2) + (size_t)kv0 * 2 + (cb ^ ((row & 7) << 4)),
                  (char*)(Vs[buf]) + w * 4096 + p * 1024);
    }
  };

  stage(0, 0);
  __syncthreads();

  const int swz = (q32 & 7) << 4;   // row&7 == q32&7 for all our LDS reads
  const int qg = qw + q32;

  for (int t = 0; t < ntiles; t++) {
    const int cur = t & 1;
    if (t + 1 < ntiles) stage(cur ^ 1, t * 64 + 64);  // prefetch under compute

#pragma unroll
    for (int half = 0; half < 2; half++) {
      const int kv0 = t * 64 + half * 32;
      if (kv0 <= qw + 31) {
        // ---- QK^T swapped, 32x32x16 (one 32-col pass)
        f32x16 s = {};
        const char* kb = (const char*)(Ks[cur]) + (half * 32 + q32) * 256;
#pragma unroll
        for (int c = 0; c < 8; c++) {
          bf16x8 kf = *(const bf16x8*)(kb + ((c * 32 + 16 * hf) ^ swz));
          s = __builtin_amdgcn_mfma_f32_32x32x16_bf16(kf, qf[c], s, 0, 0, 0);
        }

        // ---- mask + scale + per-lane max
        float pmax = -3e38f;
        if (kv0 + 31 <= qw) {               // interior pass: no mask
#pragma unroll
          for (int j = 0; j < 16; j++) { s[j] *= scl2; pmax = fmaxf(pmax, s[j]); }
        } else {
#pragma unroll
          for (int j = 0; j < 16; j++) {
            const int kvl = (j & 3) + 8 * (j >> 2) + 4 * hf;
            s[j] = (kv0 + kvl <= qg) ? s[j] * scl2 : NEGINF;
            pmax = fmaxf(pmax, s[j]);
          }
        }
        pmax = fmaxf(pmax, __shfl_xor(pmax, 32));

        // ---- online softmax, defer-max (THR=11.5 in log2 domain)
        float rs = 0.f;
        if (__all(pmax - mrow <= 11.5f)) {
#pragma unroll
          for (int j = 0; j < 16; j++) { float p = exp2f(s[j] - mrow); s[j] = p; rs += p; }
        } else {
          const float nm = fmaxf(mrow, pmax);
          const float al = exp2f(mrow - nm);
          mrow = nm;
#pragma unroll
          for (int j = 0; j < 16; j++) { float p = exp2f(s[j] - nm); s[j] = p; rs += p; }
          lsum *= al;
#pragma unroll
          for (int db = 0; db < 4; db++) of[db] *= al;
        }
        rs += __shfl_xor(rs, 32);
        lsum += rs;

        // ---- pack P pairs -> u32 words (8 live)
        int wv[8];
#pragma unroll
        for (int k = 0; k < 8; k++)
          wv[k] = (int)((unsigned)f2bf(s[2 * k]) | ((unsigned)f2bf(s[2 * k + 1]) << 16));

        // ---- PV t4=0: pB built transiently; kv local 0..15
        {
          auto ra = __builtin_amdgcn_permlane32_swap(wv[0], wv[2], false, false);
          auto rb = __builtin_amdgcn_permlane32_swap(wv[1], wv[3], false, false);
          union { int4v i; bf16x8 h; } u;
          u.i = (int4v){(int)ra[0], (int)rb[0], (int)ra[1], (int)rb[1]};
          const bf16x8 pB = u.h;
#pragma unroll
          for (int db = 0; db < 4; db++) {
            const char* vp = (const char*)(Vs[cur]) + (db * 32 + q32) * 128;
            bf16x8 vf = *(const bf16x8*)(vp + ((half * 64 + 0 + 16 * hf) ^ swz));
            of[db] = __builtin_amdgcn_mfma_f32_32x32x16_bf16(vf, pB, of[db], 0, 0, 0);
          }
        }
        // ---- PV t4=1: kv local 16..31
        {
          auto rc = __builtin_amdgcn_permlane32_swap(wv[4], wv[6], false, false);
          auto rd = __builtin_amdgcn_permlane32_swap(wv[5], wv[7], false, false);
          union { int4v i; bf16x8 h; } u2;
          u2.i = (int4v){(int)rc[0], (int)rd[0], (int)rc[1], (int)rd[1]};
          const bf16x8 pB = u2.h;
#pragma unroll
          for (int db = 0; db < 4; db++) {
            const char* vp = (const char*)(Vs[cur]) + (db * 32 + q32) * 128;
            bf16x8 vf = *(const bf16x8*)(vp + ((half * 64 + 32 + 16 * hf) ^ swz));
            of[db] = __builtin_amdgcn_mfma_f32_32x32x16_bf16(vf, pB, of[db], 0, 0, 0);
          }
        }
      }
    }
    __syncthreads();   // drains prefetch + guards buffer reuse
  }

  // ---- epilogue: of[db] reg j -> d = 32db + 8(j>>2) + 4hf + (j&3), q = qw+q32
  unsigned short* AOu = (unsigned short*)AO;
  const float inv = 1.0f / lsum;
  const size_t rowb = (size_t)(b * SEQ + qw + q32) * HID + head * HD;
#pragma unroll
  for (int db = 0; db < 4; db++) {
#pragma unroll
    for (int qd = 0; qd < 4; qd++) {
      ushort4 o;
      o.x = f2bf(of[db][4 * qd + 0] * inv);
      o.y = f2bf(of[db][4 * qd + 1] * inv);
      o.z = f2bf(of[db][4 * qd + 2] * inv);
      o.w = f2bf(of[db][4 * qd + 3] * inv);
      *(ushort4*)&AOu[rowb + db * 32 + 8 * qd + 4 * hf] = o;
    }
  }
}

// ---------------------------------------------------------------------------
extern "C" void kernel_launch(void* const* d_in, const int* in_sizes, int n_in,
                              void* d_out, int out_size, void* d_ws, size_t ws_size,
                              hipStream_t stream) {
  const float* hs = (const float*)d_in[0];
  const float* cosb = (const float*)d_in[1];
  const float* sinb = (const float*)d_in[2];
  const float* Wq = (const float*)d_in[3];
  const float* bq = (const float*)d_in[4];
  const float* Wk = (const float*)d_in[5];
  const float* bk = (const float*)d_in[6];
  const float* Wv = (const float*)d_in[7];
  const float* bv = (const float*)d_in[8];
  const float* Wo = (const float*)d_in[9];

  char* ws = (char*)d_ws;
  __hip_bfloat16* Xb = (__hip_bfloat16*)(ws);
  __hip_bfloat16* Wcat = (__hip_bfloat16*)(ws + 29360128);
  float* bcat = (float*)(ws + 62390272);
  __hip_bfloat16* QKVb = (__hip_bfloat16*)(ws + 62408704);
  __hip_bfloat16* Vt = (__hip_bfloat16*)(ws + 100157440);
  __hip_bfloat16* AOb = Xb;    // X dead after QKV GEMM
  __hip_bfloat16* Wob = Wcat;  // Wcat dead after QKV GEMM

  // Conversions to bf16
  cvt_f32_bf16<<<14336, 256, 0, stream>>>(hs, Xb, 3670016);                       // X
  cvt_f32_bf16<<<12544, 256, 0, stream>>>(Wq, Wcat, 3211264);                     // Wq rows 0..3583
  cvt_f32_bf16<<<1792, 256, 0, stream>>>(Wk, Wcat + (size_t)3584 * 3584, 458752); // Wk rows 3584..4095
  cvt_f32_bf16<<<1792, 256, 0, stream>>>(Wv, Wcat + (size_t)4096 * 3584, 458752); // Wv rows 4096..4607
  concat_bias<<<18, 256, 0, stream>>>(bq, bk, bv, bcat);

  // Fused QKV projection: [4096 x 3584] @ [4608 x 3584]^T + bias -> bf16
  gemm256<true, true><<<288, 512, 0, stream>>>(Xb, Wcat, bcat, QKVb, 4096, NQKV, HID, 16);

  // RoPE on Q + K head slots (in place, vectorized x4)
  rope_qk<<<8192, 256, 0, stream>>>(QKVb, cosb, sinb);

  // V transpose for PV fragment loads
  v_transpose<<<8192, 256, 0, stream>>>(QKVb, Vt);

  // Wo conversion (into the now-dead Wcat region)
  cvt_f32_bf16<<<12544, 256, 0, stream>>>(Wo, Wob, 3211264);

  // Flash attention: 128-row Q blocks, 4 waves x 32 rows, 64-col KV tiles.
  // Grid: x = head*2+b (56, fast axis), y = qb slot (16, slow) -> true LPT.
  dim3 ga(56, 16);
  attn_fwd<<<ga, 256, 0, stream>>>(QKVb, Vt, AOb);

  // O projection -> f32 out
  gemm256<false, false><<<224, 512, 0, stream>>>(AOb, Wob, nullptr, d_out, 4096, HID, HID, 16);
}

// Round 15
// 485.555 us; speedup vs baseline: 3.4495x; 1.0164x over previous
//
#include <hip/hip_runtime.h>
#include <hip/hip_bf16.h>

// Qwen2 attention layer, MI355X/gfx950.
// B=2 S=2048 HID=3584 NH=28 NKV=4 D=128, causal, GQA groups=7.
// Round 15 = round 14 (493.5 us) + QKV tail fix: the fused 288-block QKV
// GEMM quantized to 2 dispatch rounds (2nd round = 32 blocks, 12% util).
// Split: Q-proj (N=3584) on gemm256 -> 224 blocks = exactly one round;
// KV-proj (N=1024) on the proven 128^2 gemm_bt -> 256 quarter-size blocks.
// Both write into QKVb with ldc=4608.
//
// Workspace layout (bytes), total ~99.5 MB:
//   Xb    @ 0          29,360,128  (B*S x HID bf16)      -> reused as AOb after QKV GEMM
//   Wcat  @ 29,360,128 33,030,144  (4608 x 3584 bf16)    -> reused as Wo-bf16 after QKV GEMM
//   bcat  @ 62,390,272 18,432      (4608 f32)
//   QKVb  @ 62,408,704 37,748,736  (B*S x 4608 bf16)
//   Vt    @ 100,157,440 4,194,304  (B*NKV*128 x S bf16)

#define HID   3584
#define NHQ   28
#define NKVH  4
#define HD    128
#define SEQ   2048
#define NQKV  4608
#define GRP   7

typedef __attribute__((ext_vector_type(8))) short bf16x8;
typedef __attribute__((ext_vector_type(4))) float f32x4;
typedef __attribute__((ext_vector_type(16))) float f32x16;
typedef __attribute__((ext_vector_type(4))) int int4v;

#define BARRIER() asm volatile("s_barrier" ::: "memory")

__device__ __forceinline__ void gload_lds16(const void* g, void* l) {
  __builtin_amdgcn_global_load_lds(
      (const __attribute__((address_space(1))) void*)g,
      (__attribute__((address_space(3))) void*)l, 16, 0, 0);
}

__device__ __forceinline__ unsigned short f2bf(float f) {
  __hip_bfloat16 h = __float2bfloat16(f);
  return *reinterpret_cast<unsigned short*>(&h);
}

__device__ __forceinline__ float bf2f(unsigned short u) {
  __hip_bfloat16 h = *reinterpret_cast<__hip_bfloat16*>(&u);
  return __bfloat162float(h);
}

// ---------------- f32 -> bf16 conversion (vectorized, 4 elems/thread) ------
__global__ __launch_bounds__(256)
void cvt_f32_bf16(const float* __restrict__ src, __hip_bfloat16* __restrict__ dst, int n4) {
  int i = blockIdx.x * 256 + threadIdx.x;
  if (i >= n4) return;
  float4 v = ((const float4*)src)[i];
  ushort4 o;
  o.x = f2bf(v.x); o.y = f2bf(v.y); o.z = f2bf(v.z); o.w = f2bf(v.w);
  ((ushort4*)dst)[i] = o;
}

__global__ __launch_bounds__(256)
void concat_bias(const float* __restrict__ bq, const float* __restrict__ bk,
                 const float* __restrict__ bv, float* __restrict__ out) {
  int i = blockIdx.x * 256 + threadIdx.x;
  if (i < HID) out[i] = bq[i];
  else if (i < HID + 512) out[i] = bk[i - HID];
  else if (i < NQKV) out[i] = bv[i - HID - 512];
}

// ---------------- GEMM 256^2: C[M][N](ldc) = A[M][K] * B[N][K]^T (+bias) ---
// 256x256 tile, BK=64, 8 waves, dbuf LDS, 8-phase counted-vmcnt schedule.
// 1D grid with bijective XCD swizzle (m204).
template<bool HAS_BIAS, bool OUT_BF16>
__global__ __launch_bounds__(512, 2)
void gemm256(const __hip_bfloat16* __restrict__ A, const __hip_bfloat16* __restrict__ Bm,
             const float* __restrict__ bias, void* __restrict__ Cv,
             int M, int N, int K, int nmt, int ldc) {
  __shared__ __align__(16) char lds[131072];
  const int tid = threadIdx.x;
  const int w = tid >> 6, l = tid & 63;
  const int g = l >> 4, r = l & 15;
  const int wr = w >> 2, wc = w & 3;

  // bijective XCD swizzle (nwg % 8 == 0 for all our grids)
  const int nwg = gridDim.x;
  const int qq = nwg >> 3, r8 = nwg & 7;
  const int xcd = blockIdx.x & 7, idx = blockIdx.x >> 3;
  const int wgid = (xcd < r8 ? xcd * (qq + 1) : r8 * (qq + 1) + (xcd - r8) * qq) + idx;
  const int bm = (wgid % nmt) * 256, bn = (wgid / nmt) * 256;

  const int NKT = K >> 6;
  const size_t Kb2 = (size_t)K * 2;
  const int swz = (r & 7) << 4;

  auto issueHalf = [&](int kt, int h) {
    const char* src = (h < 2) ? (const char*)A : (const char*)Bm;
    const int rbase = (h < 2) ? bm : bn;
    char* reg = lds + (kt & 1) * 65536 + ((h < 2) ? 0 : 32768);
#pragma unroll
    for (int i = 0; i < 2; ++i) {
      const int lrow = (h & 1) * 128 + w * 16 + i * 8;   // wave-uniform dest row
      const int row = lrow + (l >> 3);                    // per-lane source row
      const int cb = (l & 7) * 16;
      gload_lds16(src + (size_t)(rbase + row) * Kb2 + (size_t)kt * 128 + (cb ^ ((row & 7) << 4)),
                  reg + lrow * 128);
    }
  };

  auto ldA = [&](int d, int mf, int kk) -> bf16x8 {
    const int row = wr * 128 + mf * 16 + r;
    return *(const bf16x8*)(lds + d * 65536 + row * 128 + ((kk * 64 + g * 16) ^ swz));
  };
  auto ldB = [&](int d, int nf, int kk) -> bf16x8 {
    const int row = wc * 64 + nf * 16 + r;
    return *(const bf16x8*)(lds + d * 65536 + 32768 + row * 128 + ((kk * 64 + g * 16) ^ swz));
  };

  f32x4 acc[8][4];
#pragma unroll
  for (int m = 0; m < 8; m++)
#pragma unroll
    for (int n = 0; n < 4; n++) acc[m][n] = (f32x4){0.f, 0.f, 0.f, 0.f};

#pragma unroll
  for (int h = 0; h < 4; ++h) issueHalf(0, h);
#pragma unroll
  for (int h = 0; h < 4; ++h) issueHalf(1, h);
  asm volatile("s_waitcnt vmcnt(8)" ::: "memory");
  BARRIER();

  bf16x8 af[4][2], bfr[4][2];

#pragma unroll 1
  for (int kt = 0; kt < NKT; ++kt) {
    const int d = kt & 1;

    if (kt >= 1 && kt + 1 < NKT) { issueHalf(kt + 1, 1); issueHalf(kt + 1, 3); }
#pragma unroll
    for (int mf = 0; mf < 4; mf++)
#pragma unroll
      for (int kk = 0; kk < 2; kk++) af[mf][kk] = ldA(d, mf, kk);
#pragma unroll
    for (int nf = 0; nf < 2; nf++)
#pragma unroll
      for (int kk = 0; kk < 2; kk++) bfr[nf][kk] = ldB(d, nf, kk);
    BARRIER();
    __builtin_amdgcn_s_setprio(1);
#pragma unroll
    for (int mf = 0; mf < 4; mf++)
#pragma unroll
      for (int nf = 0; nf < 2; nf++)
#pragma unroll
        for (int kk = 0; kk < 2; kk++)
          acc[mf][nf] = __builtin_amdgcn_mfma_f32_16x16x32_bf16(af[mf][kk], bfr[nf][kk], acc[mf][nf], 0, 0, 0);
    __builtin_amdgcn_s_setprio(0);
    BARRIER();

#pragma unroll
    for (int nf = 2; nf < 4; nf++)
#pragma unroll
      for (int kk = 0; kk < 2; kk++) bfr[nf][kk] = ldB(d, nf, kk);
    BARRIER();
    __builtin_amdgcn_s_setprio(1);
#pragma unroll
    for (int mf = 0; mf < 4; mf++)
#pragma unroll
      for (int nf = 2; nf < 4; nf++)
#pragma unroll
        for (int kk = 0; kk < 2; kk++)
          acc[mf][nf] = __builtin_amdgcn_mfma_f32_16x16x32_bf16(af[mf][kk], bfr[nf][kk], acc[mf][nf], 0, 0, 0);
    __builtin_amdgcn_s_setprio(0);
    BARRIER();

    if (kt + 2 < NKT) issueHalf(kt + 2, 2);
#pragma unroll
    for (int mf = 0; mf < 4; mf++)
#pragma unroll
      for (int kk = 0; kk < 2; kk++) af[mf][kk] = ldA(d, mf + 4, kk);
    BARRIER();
    __builtin_amdgcn_s_setprio(1);
#pragma unroll
    for (int mf = 0; mf < 4; mf++)
#pragma unroll
      for (int nf = 0; nf < 2; nf++)
#pragma unroll
        for (int kk = 0; kk < 2; kk++)
          acc[mf + 4][nf] = __builtin_amdgcn_mfma_f32_16x16x32_bf16(af[mf][kk], bfr[nf][kk], acc[mf + 4][nf], 0, 0, 0);
    __builtin_amdgcn_s_setprio(0);
    BARRIER();

    if (kt + 2 < NKT) {
      issueHalf(kt + 2, 0);
      asm volatile("s_waitcnt vmcnt(4)" ::: "memory");
    } else if (kt + 1 < NKT) {
      asm volatile("s_waitcnt vmcnt(0)" ::: "memory");
    }
    BARRIER();
    __builtin_amdgcn_s_setprio(1);
#pragma unroll
    for (int mf = 0; mf < 4; mf++)
#pragma unroll
      for (int nf = 2; nf < 4; nf++)
#pragma unroll
        for (int kk = 0; kk < 2; kk++)
          acc[mf + 4][nf] = __builtin_amdgcn_mfma_f32_16x16x32_bf16(af[mf][kk], bfr[nf][kk], acc[mf + 4][nf], 0, 0, 0);
    __builtin_amdgcn_s_setprio(0);
    BARRIER();
  }

#pragma unroll
  for (int nf = 0; nf < 4; nf++) {
    const int gcol = bn + wc * 64 + nf * 16 + r;
    const float bv = HAS_BIAS ? bias[gcol] : 0.f;
#pragma unroll
    for (int mf = 0; mf < 8; mf++) {
#pragma unroll
      for (int j = 0; j < 4; j++) {
        const int grow = bm + wr * 128 + mf * 16 + 4 * g + j;
        float v = acc[mf][nf][j] + bv;
        if constexpr (OUT_BF16)
          ((__hip_bfloat16*)Cv)[(size_t)grow * ldc + gcol] = __float2bfloat16(v);
        else
          ((float*)Cv)[(size_t)grow * ldc + gcol] = v;
      }
    }
  }
}

// ---------------- GEMM 128^2 (m97 structure, proven r1-r5) -----------------
// C[M][N](ldc) = A[M][K] * B[N][K]^T (+bias). 4 waves, BK=32, 16 KB LDS.
template<bool HAS_BIAS, bool OUT_BF16>
__global__ __launch_bounds__(256)
void gemm_bt(const __hip_bfloat16* __restrict__ A, const __hip_bfloat16* __restrict__ Bm,
             const float* __restrict__ bias, void* __restrict__ Cv,
             int M, int N, int K, int ldc) {
  __shared__ __align__(16) __hip_bfloat16 As[128 * 32];
  __shared__ __align__(16) __hip_bfloat16 Bs[128 * 32];
  const int tid = threadIdx.x;
  const int w = tid >> 6, l = tid & 63;
  const int g = l >> 4, r = l & 15;
  const int wr = w >> 1, wc = w & 1;
  const int bm = blockIdx.x * 128;
  const int bn = blockIdx.y * 128;
  const int lr = l >> 2;        // 0..15: row within a 16-row staging chunk
  const int lc = (l & 3) * 8;   // 0/8/16/24: k-col offset within chunk

  f32x4 acc[4][4];
#pragma unroll
  for (int m = 0; m < 4; m++)
#pragma unroll
    for (int n = 0; n < 4; n++) acc[m][n] = (f32x4){0.f, 0.f, 0.f, 0.f};

  for (int k0 = 0; k0 < K; k0 += 32) {
#pragma unroll
    for (int i = 0; i < 2; i++) {
      const int rb = w * 32 + i * 16;
      gload_lds16(&A[(size_t)(bm + rb + lr) * K + k0 + lc], &As[rb * 32]);
      gload_lds16(&Bm[(size_t)(bn + rb + lr) * K + k0 + lc], &Bs[rb * 32]);
    }
    __syncthreads();
    bf16x8 af[4], bfr[4];
#pragma unroll
    for (int m = 0; m < 4; m++) af[m] = *(const bf16x8*)&As[(wr * 64 + m * 16 + r) * 32 + g * 8];
#pragma unroll
    for (int n = 0; n < 4; n++) bfr[n] = *(const bf16x8*)&Bs[(wc * 64 + n * 16 + r) * 32 + g * 8];
#pragma unroll
    for (int m = 0; m < 4; m++)
#pragma unroll
      for (int n = 0; n < 4; n++)
        acc[m][n] = __builtin_amdgcn_mfma_f32_16x16x32_bf16(af[m], bfr[n], acc[m][n], 0, 0, 0);
    __syncthreads();
  }

#pragma unroll
  for (int m = 0; m < 4; m++) {
#pragma unroll
    for (int n = 0; n < 4; n++) {
      const int gcol = bn + wc * 64 + n * 16 + r;
      const float bv = HAS_BIAS ? bias[gcol] : 0.f;
#pragma unroll
      for (int j = 0; j < 4; j++) {
        const int grow = bm + wr * 64 + m * 16 + 4 * g + j;
        float v = acc[m][n][j] + bv;
        if constexpr (OUT_BF16)
          ((__hip_bfloat16*)Cv)[(size_t)grow * ldc + gcol] = __float2bfloat16(v);
        else
          ((float*)Cv)[(size_t)grow * ldc + gcol] = v;
      }
    }
  }
}

// ---------------- RoPE on Q and K head slots (in-place, bf16, x4 vec) ------
__global__ __launch_bounds__(256)
void rope_qk(__hip_bfloat16* __restrict__ QKV, const float* __restrict__ cosb,
             const float* __restrict__ sinb) {
  int i = blockIdx.x * 256 + threadIdx.x;   // 2,097,152 threads
  int d = (i & 15) * 4;
  int hh = (i >> 4) & 31;
  int row = i >> 9;
  int cb = (hh < NHQ) ? hh * HD : HID + (hh - NHQ) * HD;
  unsigned short* base = (unsigned short*)QKV + (size_t)row * NQKV + cb;
  float4 c = *(const float4*)&cosb[row * HD + d];
  float4 sn = *(const float4*)&sinb[row * HD + d];
  ushort4 u1 = *(const ushort4*)(base + d);
  ushort4 u2 = *(const ushort4*)(base + d + 64);
  float x1[4] = {bf2f(u1.x), bf2f(u1.y), bf2f(u1.z), bf2f(u1.w)};
  float x2[4] = {bf2f(u2.x), bf2f(u2.y), bf2f(u2.z), bf2f(u2.w)};
  float cc[4] = {c.x, c.y, c.z, c.w};
  float ss[4] = {sn.x, sn.y, sn.z, sn.w};
  ushort4 o1, o2;
  o1.x = f2bf(x1[0] * cc[0] - x2[0] * ss[0]); o2.x = f2bf(x2[0] * cc[0] + x1[0] * ss[0]);
  o1.y = f2bf(x1[1] * cc[1] - x2[1] * ss[1]); o2.y = f2bf(x2[1] * cc[1] + x1[1] * ss[1]);
  o1.z = f2bf(x1[2] * cc[2] - x2[2] * ss[2]); o2.z = f2bf(x2[2] * cc[2] + x1[2] * ss[2]);
  o1.w = f2bf(x1[3] * cc[3] - x2[3] * ss[3]); o2.w = f2bf(x2[3] * cc[3] + x1[3] * ss[3]);
  *(ushort4*)(base + d) = o1;
  *(ushort4*)(base + d + 64) = o2;
}

// ---------------- V transpose: Vt[b][kv][d][s] = V[b][s][kv][d] ------------
__global__ __launch_bounds__(256)
void v_transpose(const __hip_bfloat16* __restrict__ QKV, __hip_bfloat16* __restrict__ Vt) {
  int i = blockIdx.x * 256 + threadIdx.x;
  int s = i & (SEQ - 1);
  int d = (i >> 11) & (HD - 1);
  int kv = (i >> 18) & 3;
  int b = i >> 20;
  Vt[i] = QKV[(size_t)(b * SEQ + s) * NQKV + HID + 512 + kv * HD + d];
}

// ---------------- Flash attention: 32x32 MFMA, streaming 32-col passes -----
// (r11 structure + r14 LPT grid, proven.) 4 waves x 32 q-rows, KVBLK=64
// staged dbuf, compute in two 32-col passes; pB via permlane32_swap.
// Grid: x = head*2+b (fast), y = qb index (slow) -> heavy blocks first.
__global__ __launch_bounds__(256, 2)
void attn_fwd(const __hip_bfloat16* __restrict__ QKV, const __hip_bfloat16* __restrict__ Vt,
              __hip_bfloat16* __restrict__ AO) {
  const int head = blockIdx.x >> 1;         // 0..27
  const int b = blockIdx.x & 1;             // 0..1
  const int qb = 15 - blockIdx.y;           // LPT: qb=15 blocks dispatch first
  const int kvh = head / GRP;
  const int tid = threadIdx.x;
  const int w = tid >> 6, l = tid & 63;
  const int q32 = l & 31;                   // lane's q within wave tile
  const int hf = l >> 5;                    // lane half
  const int qw = qb * 128 + w * 32;         // wave's first q row
  const float scl2 = 0.12751744055204955f;  // (1/sqrt(128)) * log2(e)
  const float NEGINF = -__builtin_inff();

  __shared__ __align__(16) __hip_bfloat16 Ks[2][64 * 128];   // 2x16 KB, swizzled
  __shared__ __align__(16) __hip_bfloat16 Vs[2][128 * 64];   // 2x16 KB, swizzled

  const char* Kb = (const char*)(QKV + (size_t)(b * SEQ) * NQKV + HID + kvh * HD);
  const char* Vb = (const char*)(Vt + (size_t)((b * NKVH + kvh) * HD) * SEQ);
  const __hip_bfloat16* Qb = QKV + (size_t)(b * SEQ + qw) * NQKV + head * HD;

  // Q fragments (B-operand, 32x32x16): qf[c] = Q[qw+q32][16c + 8hf + 0..7]
  bf16x8 qf[8];
#pragma unroll
  for (int c = 0; c < 8; c++)
    qf[c] = *(const bf16x8*)&Qb[(size_t)q32 * NQKV + c * 16 + 8 * hf];

  f32x16 of[4] = {};
  float mrow = -3e38f, lsum = 0.f;

  const int ntiles = 2 * qb + 2;

  auto stage = [&](int buf, int kv0) {
#pragma unroll
    for (int p = 0; p < 4; p++) {
      const int row = w * 16 + p * 4 + (l >> 4);      // K tile row (local)
      const int cb = (l & 15) * 16;
      gload_lds16(Kb + (size_t)(kv0 + row) * (NQKV * 2) + (cb ^ ((row & 7) << 4)),
                  (char*)(Ks[buf]) + w * 4096 + p * 1024);
    }
#pragma unroll
    for (int p = 0; p < 4; p++) {
      const int row = w * 32 + p * 8 + (l >> 3);      // V^T tile row (= d)
      const int cb = (l & 7) * 16;
      gload_lds16(Vb + (size_t)row * (SEQ * 2) + (size_t)kv0 * 2 + (cb ^ ((row & 7) << 4)),
                  (char*)(Vs[buf]) + w * 4096 + p * 1024);
    }
  };

  stage(0, 0);
  __syncthreads();

  const int swz = (q32 & 7) << 4;   // row&7 == q32&7 for all our LDS reads
  const int qg = qw + q32;

  for (int t = 0; t < ntiles; t++) {
    const int cur = t & 1;
    if (t + 1 < ntiles) stage(cur ^ 1, t * 64 + 64);  // prefetch under compute

#pragma unroll
    for (int half = 0; half < 2; half++) {
      const int kv0 = t * 64 + half * 32;
      if (kv0 <= qw + 31) {
        // ---- QK^T swapped, 32x32x16 (one 32-col pass)
        f32x16 s = {};
        const char* kb = (const char*)(Ks[cur]) + (half * 32 + q32) * 256;
#pragma unroll
        for (int c = 0; c < 8; c++) {
          bf16x8 kf = *(const bf16x8*)(kb + ((c * 32 + 16 * hf) ^ swz));
          s = __builtin_amdgcn_mfma_f32_32x32x16_bf16(kf, qf[c], s, 0, 0, 0);
        }

        // ---- mask + scale + per-lane max
        float pmax = -3e38f;
        if (kv0 + 31 <= qw) {               // interior pass: no mask
#pragma unroll
          for (int j = 0; j < 16; j++) { s[j] *= scl2; pmax = fmaxf(pmax, s[j]); }
        } else {
#pragma unroll
          for (int j = 0; j < 16; j++) {
            const int kvl = (j & 3) + 8 * (j >> 2) + 4 * hf;
            s[j] = (kv0 + kvl <= qg) ? s[j] * scl2 : NEGINF;
            pmax = fmaxf(pmax, s[j]);
          }
        }
        pmax = fmaxf(pmax, __shfl_xor(pmax, 32));

        // ---- online softmax, defer-max (THR=11.5 in log2 domain)
        float rs = 0.f;
        if (__all(pmax - mrow <= 11.5f)) {
#pragma unroll
          for (int j = 0; j < 16; j++) { float p = exp2f(s[j] - mrow); s[j] = p; rs += p; }
        } else {
          const float nm = fmaxf(mrow, pmax);
          const float al = exp2f(mrow - nm);
          mrow = nm;
#pragma unroll
          for (int j = 0; j < 16; j++) { float p = exp2f(s[j] - nm); s[j] = p; rs += p; }
          lsum *= al;
#pragma unroll
          for (int db = 0; db < 4; db++) of[db] *= al;
        }
        rs += __shfl_xor(rs, 32);
        lsum += rs;

        // ---- pack P pairs -> u32 words (8 live)
        int wv[8];
#pragma unroll
        for (int k = 0; k < 8; k++)
          wv[k] = (int)((unsigned)f2bf(s[2 * k]) | ((unsigned)f2bf(s[2 * k + 1]) << 16));

        // ---- PV t4=0: pB built transiently; kv local 0..15
        {
          auto ra = __builtin_amdgcn_permlane32_swap(wv[0], wv[2], false, false);
          auto rb = __builtin_amdgcn_permlane32_swap(wv[1], wv[3], false, false);
          union { int4v i; bf16x8 h; } u;
          u.i = (int4v){(int)ra[0], (int)rb[0], (int)ra[1], (int)rb[1]};
          const bf16x8 pB = u.h;
#pragma unroll
          for (int db = 0; db < 4; db++) {
            const char* vp = (const char*)(Vs[cur]) + (db * 32 + q32) * 128;
            bf16x8 vf = *(const bf16x8*)(vp + ((half * 64 + 0 + 16 * hf) ^ swz));
            of[db] = __builtin_amdgcn_mfma_f32_32x32x16_bf16(vf, pB, of[db], 0, 0, 0);
          }
        }
        // ---- PV t4=1: kv local 16..31
        {
          auto rc = __builtin_amdgcn_permlane32_swap(wv[4], wv[6], false, false);
          auto rd = __builtin_amdgcn_permlane32_swap(wv[5], wv[7], false, false);
          union { int4v i; bf16x8 h; } u2;
          u2.i = (int4v){(int)rc[0], (int)rd[0], (int)rc[1], (int)rd[1]};
          const bf16x8 pB = u2.h;
#pragma unroll
          for (int db = 0; db < 4; db++) {
            const char* vp = (const char*)(Vs[cur]) + (db * 32 + q32) * 128;
            bf16x8 vf = *(const bf16x8*)(vp + ((half * 64 + 32 + 16 * hf) ^ swz));
            of[db] = __builtin_amdgcn_mfma_f32_32x32x16_bf16(vf, pB, of[db], 0, 0, 0);
          }
        }
      }
    }
    __syncthreads();   // drains prefetch + guards buffer reuse
  }

  // ---- epilogue: of[db] reg j -> d = 32db + 8(j>>2) + 4hf + (j&3), q = qw+q32
  unsigned short* AOu = (unsigned short*)AO;
  const float inv = 1.0f / lsum;
  const size_t rowb = (size_t)(b * SEQ + qw + q32) * HID + head * HD;
#pragma unroll
  for (int db = 0; db < 4; db++) {
#pragma unroll
    for (int qd = 0; qd < 4; qd++) {
      ushort4 o;
      o.x = f2bf(of[db][4 * qd + 0] * inv);
      o.y = f2bf(of[db][4 * qd + 1] * inv);
      o.z = f2bf(of[db][4 * qd + 2] * inv);
      o.w = f2bf(of[db][4 * qd + 3] * inv);
      *(ushort4*)&AOu[rowb + db * 32 + 8 * qd + 4 * hf] = o;
    }
  }
}

// ---------------------------------------------------------------------------
extern "C" void kernel_launch(void* const* d_in, const int* in_sizes, int n_in,
                              void* d_out, int out_size, void* d_ws, size_t ws_size,
                              hipStream_t stream) {
  const float* hs = (const float*)d_in[0];
  const float* cosb = (const float*)d_in[1];
  const float* sinb = (const float*)d_in[2];
  const float* Wq = (const float*)d_in[3];
  const float* bq = (const float*)d_in[4];
  const float* Wk = (const float*)d_in[5];
  const float* bk = (const float*)d_in[6];
  const float* Wv = (const float*)d_in[7];
  const float* bv = (const float*)d_in[8];
  const float* Wo = (const float*)d_in[9];

  char* ws = (char*)d_ws;
  __hip_bfloat16* Xb = (__hip_bfloat16*)(ws);
  __hip_bfloat16* Wcat = (__hip_bfloat16*)(ws + 29360128);
  float* bcat = (float*)(ws + 62390272);
  __hip_bfloat16* QKVb = (__hip_bfloat16*)(ws + 62408704);
  __hip_bfloat16* Vt = (__hip_bfloat16*)(ws + 100157440);
  __hip_bfloat16* AOb = Xb;    // X dead after QKV GEMM
  __hip_bfloat16* Wob = Wcat;  // Wcat dead after QKV GEMM

  // Conversions to bf16
  cvt_f32_bf16<<<14336, 256, 0, stream>>>(hs, Xb, 3670016);                       // X
  cvt_f32_bf16<<<12544, 256, 0, stream>>>(Wq, Wcat, 3211264);                     // Wq rows 0..3583
  cvt_f32_bf16<<<1792, 256, 0, stream>>>(Wk, Wcat + (size_t)3584 * 3584, 458752); // Wk rows 3584..4095
  cvt_f32_bf16<<<1792, 256, 0, stream>>>(Wv, Wcat + (size_t)4096 * 3584, 458752); // Wv rows 4096..4607
  concat_bias<<<18, 256, 0, stream>>>(bq, bk, bv, bcat);

  // Q projection: [4096 x 3584] @ Wq^T + bq -> QKVb cols 0..3583 (ldc=4608).
  // 224 blocks = exactly one dispatch round (no tail).
  gemm256<true, true><<<224, 512, 0, stream>>>(Xb, Wcat, bcat, QKVb,
                                               4096, 3584, HID, 16, NQKV);

  // KV projection: [4096 x 1024] on 128^2 tiles -> 256 quarter-size blocks.
  dim3 gkv(32, 8);
  gemm_bt<true, true><<<gkv, 256, 0, stream>>>(Xb, Wcat + (size_t)3584 * 3584,
                                               bcat + 3584, QKVb + 3584,
                                               4096, 1024, HID, NQKV);

  // RoPE on Q + K head slots (in place, vectorized x4)
  rope_qk<<<8192, 256, 0, stream>>>(QKVb, cosb, sinb);

  // V transpose for PV fragment loads
  v_transpose<<<8192, 256, 0, stream>>>(QKVb, Vt);

  // Wo conversion (into the now-dead Wcat region)
  cvt_f32_bf16<<<12544, 256, 0, stream>>>(Wo, Wob, 3211264);

  // Flash attention: 128-row Q blocks, 4 waves x 32 rows, 64-col KV tiles.
  // Grid: x = head*2+b (56, fast axis), y = qb slot (16, slow) -> true LPT.
  dim3 ga(56, 16);
  attn_fwd<<<ga, 256, 0, stream>>>(QKVb, Vt, AOb);

  // O projection -> f32 out (224 blocks, one round)
  gemm256<false, false><<<224, 512, 0, stream>>>(AOb, Wob, nullptr, d_out,
                                                 4096, HID, HID, 16, HID);
}

// Round 16
// 475.151 us; speedup vs baseline: 3.5251x; 1.0219x over previous
//
#include <hip/hip_runtime.h>
#include <hip/hip_bf16.h>

// Qwen2 attention layer, MI355X/gfx950.
// B=2 S=2048 HID=3584 NH=28 NKV=4 D=128, causal, GQA groups=7.
// Round 16 = round 15 (485.6 us) + two VALU/memory cuts:
//  - softmax scale (1/sqrt(128)*log2e) folded into Q during RoPE -> attn
//    drops 16 v_mul per 32-col pass (attn is VALU-limited: 48% vs 19% MFMA).
//  - v_transpose LDS-tiled: coalesced 16B reads + coalesced ushort4 writes.
//
// Workspace layout (bytes), total ~99.5 MB:
//   Xb    @ 0          29,360,128  (B*S x HID bf16)      -> reused as AOb after QKV GEMM
//   Wcat  @ 29,360,128 33,030,144  (4608 x 3584 bf16)    -> reused as Wo-bf16 after QKV GEMM
//   bcat  @ 62,390,272 18,432      (4608 f32)
//   QKVb  @ 62,408,704 37,748,736  (B*S x 4608 bf16)
//   Vt    @ 100,157,440 4,194,304  (B*NKV*128 x S bf16)

#define HID   3584
#define NHQ   28
#define NKVH  4
#define HD    128
#define SEQ   2048
#define NQKV  4608
#define GRP   7

typedef __attribute__((ext_vector_type(8))) short bf16x8;
typedef __attribute__((ext_vector_type(4))) float f32x4;
typedef __attribute__((ext_vector_type(16))) float f32x16;
typedef __attribute__((ext_vector_type(4))) int int4v;

#define BARRIER() asm volatile("s_barrier" ::: "memory")

__device__ __forceinline__ void gload_lds16(const void* g, void* l) {
  __builtin_amdgcn_global_load_lds(
      (const __attribute__((address_space(1))) void*)g,
      (__attribute__((address_space(3))) void*)l, 16, 0, 0);
}

__device__ __forceinline__ unsigned short f2bf(float f) {
  __hip_bfloat16 h = __float2bfloat16(f);
  return *reinterpret_cast<unsigned short*>(&h);
}

__device__ __forceinline__ float bf2f(unsigned short u) {
  __hip_bfloat16 h = *reinterpret_cast<__hip_bfloat16*>(&u);
  return __bfloat162float(h);
}

// ---------------- f32 -> bf16 conversion (vectorized, 4 elems/thread) ------
__global__ __launch_bounds__(256)
void cvt_f32_bf16(const float* __restrict__ src, __hip_bfloat16* __restrict__ dst, int n4) {
  int i = blockIdx.x * 256 + threadIdx.x;
  if (i >= n4) return;
  float4 v = ((const float4*)src)[i];
  ushort4 o;
  o.x = f2bf(v.x); o.y = f2bf(v.y); o.z = f2bf(v.z); o.w = f2bf(v.w);
  ((ushort4*)dst)[i] = o;
}

__global__ __launch_bounds__(256)
void concat_bias(const float* __restrict__ bq, const float* __restrict__ bk,
                 const float* __restrict__ bv, float* __restrict__ out) {
  int i = blockIdx.x * 256 + threadIdx.x;
  if (i < HID) out[i] = bq[i];
  else if (i < HID + 512) out[i] = bk[i - HID];
  else if (i < NQKV) out[i] = bv[i - HID - 512];
}

// ---------------- GEMM 256^2: C[M][N](ldc) = A[M][K] * B[N][K]^T (+bias) ---
// 256x256 tile, BK=64, 8 waves, dbuf LDS, 8-phase counted-vmcnt schedule.
// 1D grid with bijective XCD swizzle (m204).
template<bool HAS_BIAS, bool OUT_BF16>
__global__ __launch_bounds__(512, 2)
void gemm256(const __hip_bfloat16* __restrict__ A, const __hip_bfloat16* __restrict__ Bm,
             const float* __restrict__ bias, void* __restrict__ Cv,
             int M, int N, int K, int nmt, int ldc) {
  __shared__ __align__(16) char lds[131072];
  const int tid = threadIdx.x;
  const int w = tid >> 6, l = tid & 63;
  const int g = l >> 4, r = l & 15;
  const int wr = w >> 2, wc = w & 3;

  // bijective XCD swizzle (nwg % 8 == 0 for all our grids)
  const int nwg = gridDim.x;
  const int qq = nwg >> 3, r8 = nwg & 7;
  const int xcd = blockIdx.x & 7, idx = blockIdx.x >> 3;
  const int wgid = (xcd < r8 ? xcd * (qq + 1) : r8 * (qq + 1) + (xcd - r8) * qq) + idx;
  const int bm = (wgid % nmt) * 256, bn = (wgid / nmt) * 256;

  const int NKT = K >> 6;
  const size_t Kb2 = (size_t)K * 2;
  const int swz = (r & 7) << 4;

  auto issueHalf = [&](int kt, int h) {
    const char* src = (h < 2) ? (const char*)A : (const char*)Bm;
    const int rbase = (h < 2) ? bm : bn;
    char* reg = lds + (kt & 1) * 65536 + ((h < 2) ? 0 : 32768);
#pragma unroll
    for (int i = 0; i < 2; ++i) {
      const int lrow = (h & 1) * 128 + w * 16 + i * 8;   // wave-uniform dest row
      const int row = lrow + (l >> 3);                    // per-lane source row
      const int cb = (l & 7) * 16;
      gload_lds16(src + (size_t)(rbase + row) * Kb2 + (size_t)kt * 128 + (cb ^ ((row & 7) << 4)),
                  reg + lrow * 128);
    }
  };

  auto ldA = [&](int d, int mf, int kk) -> bf16x8 {
    const int row = wr * 128 + mf * 16 + r;
    return *(const bf16x8*)(lds + d * 65536 + row * 128 + ((kk * 64 + g * 16) ^ swz));
  };
  auto ldB = [&](int d, int nf, int kk) -> bf16x8 {
    const int row = wc * 64 + nf * 16 + r;
    return *(const bf16x8*)(lds + d * 65536 + 32768 + row * 128 + ((kk * 64 + g * 16) ^ swz));
  };

  f32x4 acc[8][4];
#pragma unroll
  for (int m = 0; m < 8; m++)
#pragma unroll
    for (int n = 0; n < 4; n++) acc[m][n] = (f32x4){0.f, 0.f, 0.f, 0.f};

#pragma unroll
  for (int h = 0; h < 4; ++h) issueHalf(0, h);
#pragma unroll
  for (int h = 0; h < 4; ++h) issueHalf(1, h);
  asm volatile("s_waitcnt vmcnt(8)" ::: "memory");
  BARRIER();

  bf16x8 af[4][2], bfr[4][2];

#pragma unroll 1
  for (int kt = 0; kt < NKT; ++kt) {
    const int d = kt & 1;

    if (kt >= 1 && kt + 1 < NKT) { issueHalf(kt + 1, 1); issueHalf(kt + 1, 3); }
#pragma unroll
    for (int mf = 0; mf < 4; mf++)
#pragma unroll
      for (int kk = 0; kk < 2; kk++) af[mf][kk] = ldA(d, mf, kk);
#pragma unroll
    for (int nf = 0; nf < 2; nf++)
#pragma unroll
      for (int kk = 0; kk < 2; kk++) bfr[nf][kk] = ldB(d, nf, kk);
    BARRIER();
    __builtin_amdgcn_s_setprio(1);
#pragma unroll
    for (int mf = 0; mf < 4; mf++)
#pragma unroll
      for (int nf = 0; nf < 2; nf++)
#pragma unroll
        for (int kk = 0; kk < 2; kk++)
          acc[mf][nf] = __builtin_amdgcn_mfma_f32_16x16x32_bf16(af[mf][kk], bfr[nf][kk], acc[mf][nf], 0, 0, 0);
    __builtin_amdgcn_s_setprio(0);
    BARRIER();

#pragma unroll
    for (int nf = 2; nf < 4; nf++)
#pragma unroll
      for (int kk = 0; kk < 2; kk++) bfr[nf][kk] = ldB(d, nf, kk);
    BARRIER();
    __builtin_amdgcn_s_setprio(1);
#pragma unroll
    for (int mf = 0; mf < 4; mf++)
#pragma unroll
      for (int nf = 2; nf < 4; nf++)
#pragma unroll
        for (int kk = 0; kk < 2; kk++)
          acc[mf][nf] = __builtin_amdgcn_mfma_f32_16x16x32_bf16(af[mf][kk], bfr[nf][kk], acc[mf][nf], 0, 0, 0);
    __builtin_amdgcn_s_setprio(0);
    BARRIER();

    if (kt + 2 < NKT) issueHalf(kt + 2, 2);
#pragma unroll
    for (int mf = 0; mf < 4; mf++)
#pragma unroll
      for (int kk = 0; kk < 2; kk++) af[mf][kk] = ldA(d, mf + 4, kk);
    BARRIER();
    __builtin_amdgcn_s_setprio(1);
#pragma unroll
    for (int mf = 0; mf < 4; mf++)
#pragma unroll
      for (int nf = 0; nf < 2; nf++)
#pragma unroll
        for (int kk = 0; kk < 2; kk++)
          acc[mf + 4][nf] = __builtin_amdgcn_mfma_f32_16x16x32_bf16(af[mf][kk], bfr[nf][kk], acc[mf + 4][nf], 0, 0, 0);
    __builtin_amdgcn_s_setprio(0);
    BARRIER();

    if (kt + 2 < NKT) {
      issueHalf(kt + 2, 0);
      asm volatile("s_waitcnt vmcnt(4)" ::: "memory");
    } else if (kt + 1 < NKT) {
      asm volatile("s_waitcnt vmcnt(0)" ::: "memory");
    }
    BARRIER();
    __builtin_amdgcn_s_setprio(1);
#pragma unroll
    for (int mf = 0; mf < 4; mf++)
#pragma unroll
      for (int nf = 2; nf < 4; nf++)
#pragma unroll
        for (int kk = 0; kk < 2; kk++)
          acc[mf + 4][nf] = __builtin_amdgcn_mfma_f32_16x16x32_bf16(af[mf][kk], bfr[nf][kk], acc[mf + 4][nf], 0, 0, 0);
    __builtin_amdgcn_s_setprio(0);
    BARRIER();
  }

#pragma unroll
  for (int nf = 0; nf < 4; nf++) {
    const int gcol = bn + wc * 64 + nf * 16 + r;
    const float bv = HAS_BIAS ? bias[gcol] : 0.f;
#pragma unroll
    for (int mf = 0; mf < 8; mf++) {
#pragma unroll
      for (int j = 0; j < 4; j++) {
        const int grow = bm + wr * 128 + mf * 16 + 4 * g + j;
        float v = acc[mf][nf][j] + bv;
        if constexpr (OUT_BF16)
          ((__hip_bfloat16*)Cv)[(size_t)grow * ldc + gcol] = __float2bfloat16(v);
        else
          ((float*)Cv)[(size_t)grow * ldc + gcol] = v;
      }
    }
  }
}

// ---------------- GEMM 128^2 (m97 structure, proven r1-r5) -----------------
// C[M][N](ldc) = A[M][K] * B[N][K]^T (+bias). 4 waves, BK=32, 16 KB LDS.
template<bool HAS_BIAS, bool OUT_BF16>
__global__ __launch_bounds__(256)
void gemm_bt(const __hip_bfloat16* __restrict__ A, const __hip_bfloat16* __restrict__ Bm,
             const float* __restrict__ bias, void* __restrict__ Cv,
             int M, int N, int K, int ldc) {
  __shared__ __align__(16) __hip_bfloat16 As[128 * 32];
  __shared__ __align__(16) __hip_bfloat16 Bs[128 * 32];
  const int tid = threadIdx.x;
  const int w = tid >> 6, l = tid & 63;
  const int g = l >> 4, r = l & 15;
  const int wr = w >> 1, wc = w & 1;
  const int bm = blockIdx.x * 128;
  const int bn = blockIdx.y * 128;
  const int lr = l >> 2;        // 0..15: row within a 16-row staging chunk
  const int lc = (l & 3) * 8;   // 0/8/16/24: k-col offset within chunk

  f32x4 acc[4][4];
#pragma unroll
  for (int m = 0; m < 4; m++)
#pragma unroll
    for (int n = 0; n < 4; n++) acc[m][n] = (f32x4){0.f, 0.f, 0.f, 0.f};

  for (int k0 = 0; k0 < K; k0 += 32) {
#pragma unroll
    for (int i = 0; i < 2; i++) {
      const int rb = w * 32 + i * 16;
      gload_lds16(&A[(size_t)(bm + rb + lr) * K + k0 + lc], &As[rb * 32]);
      gload_lds16(&Bm[(size_t)(bn + rb + lr) * K + k0 + lc], &Bs[rb * 32]);
    }
    __syncthreads();
    bf16x8 af[4], bfr[4];
#pragma unroll
    for (int m = 0; m < 4; m++) af[m] = *(const bf16x8*)&As[(wr * 64 + m * 16 + r) * 32 + g * 8];
#pragma unroll
    for (int n = 0; n < 4; n++) bfr[n] = *(const bf16x8*)&Bs[(wc * 64 + n * 16 + r) * 32 + g * 8];
#pragma unroll
    for (int m = 0; m < 4; m++)
#pragma unroll
      for (int n = 0; n < 4; n++)
        acc[m][n] = __builtin_amdgcn_mfma_f32_16x16x32_bf16(af[m], bfr[n], acc[m][n], 0, 0, 0);
    __syncthreads();
  }

#pragma unroll
  for (int m = 0; m < 4; m++) {
#pragma unroll
    for (int n = 0; n < 4; n++) {
      const int gcol = bn + wc * 64 + n * 16 + r;
      const float bv = HAS_BIAS ? bias[gcol] : 0.f;
#pragma unroll
      for (int j = 0; j < 4; j++) {
        const int grow = bm + wr * 64 + m * 16 + 4 * g + j;
        float v = acc[m][n][j] + bv;
        if constexpr (OUT_BF16)
          ((__hip_bfloat16*)Cv)[(size_t)grow * ldc + gcol] = __float2bfloat16(v);
        else
          ((float*)Cv)[(size_t)grow * ldc + gcol] = v;
      }
    }
  }
}

// ---------------- RoPE on Q and K head slots (in-place, bf16, x4 vec) ------
// Q heads additionally scaled by scl2 = (1/sqrt(128))*log2(e): folds the
// softmax scale into Q so attn's per-pass v_mul disappears.
__global__ __launch_bounds__(256)
void rope_qk(__hip_bfloat16* __restrict__ QKV, const float* __restrict__ cosb,
             const float* __restrict__ sinb) {
  int i = blockIdx.x * 256 + threadIdx.x;   // 2,097,152 threads
  int d = (i & 15) * 4;
  int hh = (i >> 4) & 31;
  int row = i >> 9;
  int cb = (hh < NHQ) ? hh * HD : HID + (hh - NHQ) * HD;
  const float qs = (hh < NHQ) ? 0.12751744055204955f : 1.0f;
  unsigned short* base = (unsigned short*)QKV + (size_t)row * NQKV + cb;
  float4 c = *(const float4*)&cosb[row * HD + d];
  float4 sn = *(const float4*)&sinb[row * HD + d];
  ushort4 u1 = *(const ushort4*)(base + d);
  ushort4 u2 = *(const ushort4*)(base + d + 64);
  float x1[4] = {bf2f(u1.x), bf2f(u1.y), bf2f(u1.z), bf2f(u1.w)};
  float x2[4] = {bf2f(u2.x), bf2f(u2.y), bf2f(u2.z), bf2f(u2.w)};
  float cc[4] = {c.x, c.y, c.z, c.w};
  float ss[4] = {sn.x, sn.y, sn.z, sn.w};
  ushort4 o1, o2;
  o1.x = f2bf((x1[0] * cc[0] - x2[0] * ss[0]) * qs); o2.x = f2bf((x2[0] * cc[0] + x1[0] * ss[0]) * qs);
  o1.y = f2bf((x1[1] * cc[1] - x2[1] * ss[1]) * qs); o2.y = f2bf((x2[1] * cc[1] + x1[1] * ss[1]) * qs);
  o1.z = f2bf((x1[2] * cc[2] - x2[2] * ss[2]) * qs); o2.z = f2bf((x2[2] * cc[2] + x1[2] * ss[2]) * qs);
  o1.w = f2bf((x1[3] * cc[3] - x2[3] * ss[3]) * qs); o2.w = f2bf((x2[3] * cc[3] + x1[3] * ss[3]) * qs);
  *(ushort4*)(base + d) = o1;
  *(ushort4*)(base + d + 64) = o2;
}

// ---------------- V transpose (LDS-tiled, coalesced both sides) ------------
// Tile: 64 s-rows x 128 d. Read: 16B/lane row segments; write: ushort4
// contiguous in s. Grid: 256 blocks (b*128 + kv*32 + s-tile).
__global__ __launch_bounds__(256)
void v_transpose(const __hip_bfloat16* __restrict__ QKV, __hip_bfloat16* __restrict__ Vt) {
  __shared__ ushort tile[64][136];   // +8 pad: 16B-aligned rows, conflict-light
  const int st = blockIdx.x & 31, kv = (blockIdx.x >> 5) & 3, b = blockIdx.x >> 7;
  const int s0 = st * 64;
  const int t = threadIdx.x;
  const int sl = t >> 4, dv = (t & 15) * 8;
  const ushort* src = (const ushort*)QKV + (size_t)(b * SEQ) * NQKV + HID + 512 + kv * HD;
#pragma unroll
  for (int p = 0; p < 4; p++) {
    const int s = s0 + p * 16 + sl;
    *(uint4*)&tile[p * 16 + sl][dv] = *(const uint4*)&src[(size_t)s * NQKV + dv];
  }
  __syncthreads();
  ushort* dst = (ushort*)Vt + (size_t)((b * NKVH + kv) * HD) * SEQ;
#pragma unroll
  for (int it = 0; it < 8; it++) {
    const int idx = it * 256 + t;
    const int d = idx >> 4, sg = idx & 15;
    ushort4 o;
    o.x = tile[sg * 4 + 0][d];
    o.y = tile[sg * 4 + 1][d];
    o.z = tile[sg * 4 + 2][d];
    o.w = tile[sg * 4 + 3][d];
    *(ushort4*)&dst[(size_t)d * SEQ + s0 + sg * 4] = o;
  }
}

// ---------------- Flash attention: 32x32 MFMA, streaming 32-col passes -----
// (r11 structure + r14 LPT grid.) 4 waves x 32 q-rows, KVBLK=64 staged
// dbuf, two 32-col passes; pB via permlane32_swap. Q pre-scaled by scl2
// in rope -> no per-pass scale mul.
__global__ __launch_bounds__(256, 2)
void attn_fwd(const __hip_bfloat16* __restrict__ QKV, const __hip_bfloat16* __restrict__ Vt,
              __hip_bfloat16* __restrict__ AO) {
  const int head = blockIdx.x >> 1;         // 0..27
  const int b = blockIdx.x & 1;             // 0..1
  const int qb = 15 - blockIdx.y;           // LPT: qb=15 blocks dispatch first
  const int kvh = head / GRP;
  const int tid = threadIdx.x;
  const int w = tid >> 6, l = tid & 63;
  const int q32 = l & 31;                   // lane's q within wave tile
  const int hf = l >> 5;                    // lane half
  const int qw = qb * 128 + w * 32;         // wave's first q row
  const float NEGINF = -__builtin_inff();

  __shared__ __align__(16) __hip_bfloat16 Ks[2][64 * 128];   // 2x16 KB, swizzled
  __shared__ __align__(16) __hip_bfloat16 Vs[2][128 * 64];   // 2x16 KB, swizzled

  const char* Kb = (const char*)(QKV + (size_t)(b * SEQ) * NQKV + HID + kvh * HD);
  const char* Vb = (const char*)(Vt + (size_t)((b * NKVH + kvh) * HD) * SEQ);
  const __hip_bfloat16* Qb = QKV + (size_t)(b * SEQ + qw) * NQKV + head * HD;

  // Q fragments (B-operand, 32x32x16): qf[c] = Q[qw+q32][16c + 8hf + 0..7]
  bf16x8 qf[8];
#pragma unroll
  for (int c = 0; c < 8; c++)
    qf[c] = *(const bf16x8*)&Qb[(size_t)q32 * NQKV + c * 16 + 8 * hf];

  f32x16 of[4] = {};
  float mrow = -3e38f, lsum = 0.f;

  const int ntiles = 2 * qb + 2;

  auto stage = [&](int buf, int kv0) {
#pragma unroll
    for (int p = 0; p < 4; p++) {
      const int row = w * 16 + p * 4 + (l >> 4);      // K tile row (local)
      const int cb = (l & 15) * 16;
      gload_lds16(Kb + (size_t)(kv0 + row) * (NQKV * 2) + (cb ^ ((row & 7) << 4)),
                  (char*)(Ks[buf]) + w * 4096 + p * 1024);
    }
#pragma unroll
    for (int p = 0; p < 4; p++) {
      const int row = w * 32 + p * 8 + (l >> 3);      // V^T tile row (= d)
      const int cb = (l & 7) * 16;
      gload_lds16(Vb + (size_t)row * (SEQ * 2) + (size_t)kv0 * 2 + (cb ^ ((row & 7) << 4)),
                  (char*)(Vs[buf]) + w * 4096 + p * 1024);
    }
  };

  stage(0, 0);
  __syncthreads();

  const int swz = (q32 & 7) << 4;   // row&7 == q32&7 for all our LDS reads
  const int qg = qw + q32;

  for (int t = 0; t < ntiles; t++) {
    const int cur = t & 1;
    if (t + 1 < ntiles) stage(cur ^ 1, t * 64 + 64);  // prefetch under compute

#pragma unroll
    for (int half = 0; half < 2; half++) {
      const int kv0 = t * 64 + half * 32;
      if (kv0 <= qw + 31) {
        // ---- QK^T swapped, 32x32x16 (one 32-col pass); Q pre-scaled
        f32x16 s = {};
        const char* kb = (const char*)(Ks[cur]) + (half * 32 + q32) * 256;
#pragma unroll
        for (int c = 0; c < 8; c++) {
          bf16x8 kf = *(const bf16x8*)(kb + ((c * 32 + 16 * hf) ^ swz));
          s = __builtin_amdgcn_mfma_f32_32x32x16_bf16(kf, qf[c], s, 0, 0, 0);
        }

        // ---- mask + per-lane max (no scale mul: folded into Q)
        float pmax = -3e38f;
        if (kv0 + 31 <= qw) {               // interior pass: no mask
#pragma unroll
          for (int j = 0; j < 16; j++) pmax = fmaxf(pmax, s[j]);
        } else {
#pragma unroll
          for (int j = 0; j < 16; j++) {
            const int kvl = (j & 3) + 8 * (j >> 2) + 4 * hf;
            s[j] = (kv0 + kvl <= qg) ? s[j] : NEGINF;
            pmax = fmaxf(pmax, s[j]);
          }
        }
        pmax = fmaxf(pmax, __shfl_xor(pmax, 32));

        // ---- online softmax, defer-max (THR=11.5 in log2 domain)
        float rs = 0.f;
        if (__all(pmax - mrow <= 11.5f)) {
#pragma unroll
          for (int j = 0; j < 16; j++) { float p = exp2f(s[j] - mrow); s[j] = p; rs += p; }
        } else {
          const float nm = fmaxf(mrow, pmax);
          const float al = exp2f(mrow - nm);
          mrow = nm;
#pragma unroll
          for (int j = 0; j < 16; j++) { float p = exp2f(s[j] - nm); s[j] = p; rs += p; }
          lsum *= al;
#pragma unroll
          for (int db = 0; db < 4; db++) of[db] *= al;
        }
        rs += __shfl_xor(rs, 32);
        lsum += rs;

        // ---- pack P pairs -> u32 words (8 live)
        int wv[8];
#pragma unroll
        for (int k = 0; k < 8; k++)
          wv[k] = (int)((unsigned)f2bf(s[2 * k]) | ((unsigned)f2bf(s[2 * k + 1]) << 16));

        // ---- PV t4=0: pB built transiently; kv local 0..15
        {
          auto ra = __builtin_amdgcn_permlane32_swap(wv[0], wv[2], false, false);
          auto rb = __builtin_amdgcn_permlane32_swap(wv[1], wv[3], false, false);
          union { int4v i; bf16x8 h; } u;
          u.i = (int4v){(int)ra[0], (int)rb[0], (int)ra[1], (int)rb[1]};
          const bf16x8 pB = u.h;
#pragma unroll
          for (int db = 0; db < 4; db++) {
            const char* vp = (const char*)(Vs[cur]) + (db * 32 + q32) * 128;
            bf16x8 vf = *(const bf16x8*)(vp + ((half * 64 + 0 + 16 * hf) ^ swz));
            of[db] = __builtin_amdgcn_mfma_f32_32x32x16_bf16(vf, pB, of[db], 0, 0, 0);
          }
        }
        // ---- PV t4=1: kv local 16..31
        {
          auto rc = __builtin_amdgcn_permlane32_swap(wv[4], wv[6], false, false);
          auto rd = __builtin_amdgcn_permlane32_swap(wv[5], wv[7], false, false);
          union { int4v i; bf16x8 h; } u2;
          u2.i = (int4v){(int)rc[0], (int)rd[0], (int)rc[1], (int)rd[1]};
          const bf16x8 pB = u2.h;
#pragma unroll
          for (int db = 0; db < 4; db++) {
            const char* vp = (const char*)(Vs[cur]) + (db * 32 + q32) * 128;
            bf16x8 vf = *(const bf16x8*)(vp + ((half * 64 + 32 + 16 * hf) ^ swz));
            of[db] = __builtin_amdgcn_mfma_f32_32x32x16_bf16(vf, pB, of[db], 0, 0, 0);
          }
        }
      }
    }
    __syncthreads();   // drains prefetch + guards buffer reuse
  }

  // ---- epilogue: of[db] reg j -> d = 32db + 8(j>>2) + 4hf + (j&3), q = qw+q32
  unsigned short* AOu = (unsigned short*)AO;
  const float inv = 1.0f / lsum;
  const size_t rowb = (size_t)(b * SEQ + qw + q32) * HID + head * HD;
#pragma unroll
  for (int db = 0; db < 4; db++) {
#pragma unroll
    for (int qd = 0; qd < 4; qd++) {
      ushort4 o;
      o.x = f2bf(of[db][4 * qd + 0] * inv);
      o.y = f2bf(of[db][4 * qd + 1] * inv);
      o.z = f2bf(of[db][4 * qd + 2] * inv);
      o.w = f2bf(of[db][4 * qd + 3] * inv);
      *(ushort4*)&AOu[rowb + db * 32 + 8 * qd + 4 * hf] = o;
    }
  }
}

// ---------------------------------------------------------------------------
extern "C" void kernel_launch(void* const* d_in, const int* in_sizes, int n_in,
                              void* d_out, int out_size, void* d_ws, size_t ws_size,
                              hipStream_t stream) {
  const float* hs = (const float*)d_in[0];
  const float* cosb = (const float*)d_in[1];
  const float* sinb = (const float*)d_in[2];
  const float* Wq = (const float*)d_in[3];
  const float* bq = (const float*)d_in[4];
  const float* Wk = (const float*)d_in[5];
  const float* bk = (const float*)d_in[6];
  const float* Wv = (const float*)d_in[7];
  const float* bv = (const float*)d_in[8];
  const float* Wo = (const float*)d_in[9];

  char* ws = (char*)d_ws;
  __hip_bfloat16* Xb = (__hip_bfloat16*)(ws);
  __hip_bfloat16* Wcat = (__hip_bfloat16*)(ws + 29360128);
  float* bcat = (float*)(ws + 62390272);
  __hip_bfloat16* QKVb = (__hip_bfloat16*)(ws + 62408704);
  __hip_bfloat16* Vt = (__hip_bfloat16*)(ws + 100157440);
  __hip_bfloat16* AOb = Xb;    // X dead after QKV GEMM
  __hip_bfloat16* Wob = Wcat;  // Wcat dead after QKV GEMM

  // Conversions to bf16
  cvt_f32_bf16<<<14336, 256, 0, stream>>>(hs, Xb, 3670016);                       // X
  cvt_f32_bf16<<<12544, 256, 0, stream>>>(Wq, Wcat, 3211264);                     // Wq rows 0..3583
  cvt_f32_bf16<<<1792, 256, 0, stream>>>(Wk, Wcat + (size_t)3584 * 3584, 458752); // Wk rows 3584..4095
  cvt_f32_bf16<<<1792, 256, 0, stream>>>(Wv, Wcat + (size_t)4096 * 3584, 458752); // Wv rows 4096..4607
  concat_bias<<<18, 256, 0, stream>>>(bq, bk, bv, bcat);

  // Q projection: [4096 x 3584] @ Wq^T + bq -> QKVb cols 0..3583 (ldc=4608).
  gemm256<true, true><<<224, 512, 0, stream>>>(Xb, Wcat, bcat, QKVb,
                                               4096, 3584, HID, 16, NQKV);

  // KV projection: [4096 x 1024] on 128^2 tiles -> 256 quarter-size blocks.
  dim3 gkv(32, 8);
  gemm_bt<true, true><<<gkv, 256, 0, stream>>>(Xb, Wcat + (size_t)3584 * 3584,
                                               bcat + 3584, QKVb + 3584,
                                               4096, 1024, HID, NQKV);

  // RoPE on Q + K head slots (in place; Q pre-scaled by scl2)
  rope_qk<<<8192, 256, 0, stream>>>(QKVb, cosb, sinb);

  // V transpose (LDS-tiled, coalesced)
  v_transpose<<<256, 256, 0, stream>>>(QKVb, Vt);

  // Wo conversion (into the now-dead Wcat region)
  cvt_f32_bf16<<<12544, 256, 0, stream>>>(Wo, Wob, 3211264);

  // Flash attention: 128-row Q blocks, 4 waves x 32 rows, 64-col KV tiles.
  dim3 ga(56, 16);
  attn_fwd<<<ga, 256, 0, stream>>>(QKVb, Vt, AOb);

  // O projection -> f32 out (224 blocks, one round)
  gemm256<false, false><<<224, 512, 0, stream>>>(AOb, Wob, nullptr, d_out,
                                                 4096, HID, HID, 16, HID);
}

// Round 17
// 467.568 us; speedup vs baseline: 3.5822x; 1.0162x over previous
//
#include <hip/hip_runtime.h>
#include <hip/hip_bf16.h>

// Qwen2 attention layer, MI355X/gfx950.
// B=2 S=2048 HID=3584 NH=28 NKV=4 D=128, causal, GQA groups=7.
// Round 17 = round 16 (475.2 us) + three cuts:
//  - projections re-split as QK (N=4096 -> 256 blocks = exactly one full
//    round on 256 CUs) + V (N=512 -> 128 gemm_bt blocks, ~20 us).
//  - X/Wq/Wk/Wv conversions fused into one range-dispatched kernel.
//  - attn: lsum cross-half shfl deferred to epilogue (al identical across
//    lane-halves since pmax is shared).
//
// Workspace layout (bytes), total ~99.5 MB:
//   Xb    @ 0          29,360,128  (B*S x HID bf16)      -> reused as AOb after QKV GEMM
//   Wcat  @ 29,360,128 33,030,144  (4608 x 3584 bf16)    -> reused as Wo-bf16 after QK GEMM
//   bcat  @ 62,390,272 18,432      (4608 f32)
//   QKVb  @ 62,408,704 37,748,736  (B*S x 4608 bf16)
//   Vt    @ 100,157,440 4,194,304  (B*NKV*128 x S bf16)

#define HID   3584
#define NHQ   28
#define NKVH  4
#define HD    128
#define SEQ   2048
#define NQKV  4608
#define GRP   7

typedef __attribute__((ext_vector_type(8))) short bf16x8;
typedef __attribute__((ext_vector_type(4))) float f32x4;
typedef __attribute__((ext_vector_type(16))) float f32x16;
typedef __attribute__((ext_vector_type(4))) int int4v;

#define BARRIER() asm volatile("s_barrier" ::: "memory")

__device__ __forceinline__ void gload_lds16(const void* g, void* l) {
  __builtin_amdgcn_global_load_lds(
      (const __attribute__((address_space(1))) void*)g,
      (__attribute__((address_space(3))) void*)l, 16, 0, 0);
}

__device__ __forceinline__ unsigned short f2bf(float f) {
  __hip_bfloat16 h = __float2bfloat16(f);
  return *reinterpret_cast<unsigned short*>(&h);
}

__device__ __forceinline__ float bf2f(unsigned short u) {
  __hip_bfloat16 h = *reinterpret_cast<__hip_bfloat16*>(&u);
  return __bfloat162float(h);
}

// ---------------- fused f32 -> bf16 conversion (X, Wq, Wk, Wv) -------------
// Ranges in f32x4 units: X 3,670,016 | Wq 3,211,264 | Wk 458,752 | Wv 458,752
__global__ __launch_bounds__(256)
void cvt_fused(const float* __restrict__ X, const float* __restrict__ Wq,
               const float* __restrict__ Wk, const float* __restrict__ Wv,
               __hip_bfloat16* __restrict__ Xb, __hip_bfloat16* __restrict__ Wcat) {
  int i = blockIdx.x * 256 + threadIdx.x;   // 0 .. 7,798,783
  const float* src;
  __hip_bfloat16* dst;
  int off;
  if (i < 3670016)      { src = X;  dst = Xb;   off = i; }
  else if (i < 6881280) { src = Wq; dst = Wcat; off = i - 3670016; }
  else if (i < 7340032) { src = Wk; dst = Wcat + (size_t)3584 * 3584; off = i - 6881280; }
  else                  { src = Wv; dst = Wcat + (size_t)4096 * 3584; off = i - 7340032; }
  float4 v = ((const float4*)src)[off];
  ushort4 o;
  o.x = f2bf(v.x); o.y = f2bf(v.y); o.z = f2bf(v.z); o.w = f2bf(v.w);
  ((ushort4*)dst)[off] = o;
}

__global__ __launch_bounds__(256)
void cvt_f32_bf16(const float* __restrict__ src, __hip_bfloat16* __restrict__ dst, int n4) {
  int i = blockIdx.x * 256 + threadIdx.x;
  if (i >= n4) return;
  float4 v = ((const float4*)src)[i];
  ushort4 o;
  o.x = f2bf(v.x); o.y = f2bf(v.y); o.z = f2bf(v.z); o.w = f2bf(v.w);
  ((ushort4*)dst)[i] = o;
}

__global__ __launch_bounds__(256)
void concat_bias(const float* __restrict__ bq, const float* __restrict__ bk,
                 const float* __restrict__ bv, float* __restrict__ out) {
  int i = blockIdx.x * 256 + threadIdx.x;
  if (i < HID) out[i] = bq[i];
  else if (i < HID + 512) out[i] = bk[i - HID];
  else if (i < NQKV) out[i] = bv[i - HID - 512];
}

// ---------------- GEMM 256^2: C[M][N](ldc) = A[M][K] * B[N][K]^T (+bias) ---
// 256x256 tile, BK=64, 8 waves, dbuf LDS, 8-phase counted-vmcnt schedule.
// 1D grid with bijective XCD swizzle (m204).
template<bool HAS_BIAS, bool OUT_BF16>
__global__ __launch_bounds__(512, 2)
void gemm256(const __hip_bfloat16* __restrict__ A, const __hip_bfloat16* __restrict__ Bm,
             const float* __restrict__ bias, void* __restrict__ Cv,
             int M, int N, int K, int nmt, int ldc) {
  __shared__ __align__(16) char lds[131072];
  const int tid = threadIdx.x;
  const int w = tid >> 6, l = tid & 63;
  const int g = l >> 4, r = l & 15;
  const int wr = w >> 2, wc = w & 3;

  // bijective XCD swizzle (nwg % 8 == 0 for all our grids)
  const int nwg = gridDim.x;
  const int qq = nwg >> 3, r8 = nwg & 7;
  const int xcd = blockIdx.x & 7, idx = blockIdx.x >> 3;
  const int wgid = (xcd < r8 ? xcd * (qq + 1) : r8 * (qq + 1) + (xcd - r8) * qq) + idx;
  const int bm = (wgid % nmt) * 256, bn = (wgid / nmt) * 256;

  const int NKT = K >> 6;
  const size_t Kb2 = (size_t)K * 2;
  const int swz = (r & 7) << 4;

  auto issueHalf = [&](int kt, int h) {
    const char* src = (h < 2) ? (const char*)A : (const char*)Bm;
    const int rbase = (h < 2) ? bm : bn;
    char* reg = lds + (kt & 1) * 65536 + ((h < 2) ? 0 : 32768);
#pragma unroll
    for (int i = 0; i < 2; ++i) {
      const int lrow = (h & 1) * 128 + w * 16 + i * 8;   // wave-uniform dest row
      const int row = lrow + (l >> 3);                    // per-lane source row
      const int cb = (l & 7) * 16;
      gload_lds16(src + (size_t)(rbase + row) * Kb2 + (size_t)kt * 128 + (cb ^ ((row & 7) << 4)),
                  reg + lrow * 128);
    }
  };

  auto ldA = [&](int d, int mf, int kk) -> bf16x8 {
    const int row = wr * 128 + mf * 16 + r;
    return *(const bf16x8*)(lds + d * 65536 + row * 128 + ((kk * 64 + g * 16) ^ swz));
  };
  auto ldB = [&](int d, int nf, int kk) -> bf16x8 {
    const int row = wc * 64 + nf * 16 + r;
    return *(const bf16x8*)(lds + d * 65536 + 32768 + row * 128 + ((kk * 64 + g * 16) ^ swz));
  };

  f32x4 acc[8][4];
#pragma unroll
  for (int m = 0; m < 8; m++)
#pragma unroll
    for (int n = 0; n < 4; n++) acc[m][n] = (f32x4){0.f, 0.f, 0.f, 0.f};

#pragma unroll
  for (int h = 0; h < 4; ++h) issueHalf(0, h);
#pragma unroll
  for (int h = 0; h < 4; ++h) issueHalf(1, h);
  asm volatile("s_waitcnt vmcnt(8)" ::: "memory");
  BARRIER();

  bf16x8 af[4][2], bfr[4][2];

#pragma unroll 1
  for (int kt = 0; kt < NKT; ++kt) {
    const int d = kt & 1;

    if (kt >= 1 && kt + 1 < NKT) { issueHalf(kt + 1, 1); issueHalf(kt + 1, 3); }
#pragma unroll
    for (int mf = 0; mf < 4; mf++)
#pragma unroll
      for (int kk = 0; kk < 2; kk++) af[mf][kk] = ldA(d, mf, kk);
#pragma unroll
    for (int nf = 0; nf < 2; nf++)
#pragma unroll
      for (int kk = 0; kk < 2; kk++) bfr[nf][kk] = ldB(d, nf, kk);
    BARRIER();
    __builtin_amdgcn_s_setprio(1);
#pragma unroll
    for (int mf = 0; mf < 4; mf++)
#pragma unroll
      for (int nf = 0; nf < 2; nf++)
#pragma unroll
        for (int kk = 0; kk < 2; kk++)
          acc[mf][nf] = __builtin_amdgcn_mfma_f32_16x16x32_bf16(af[mf][kk], bfr[nf][kk], acc[mf][nf], 0, 0, 0);
    __builtin_amdgcn_s_setprio(0);
    BARRIER();

#pragma unroll
    for (int nf = 2; nf < 4; nf++)
#pragma unroll
      for (int kk = 0; kk < 2; kk++) bfr[nf][kk] = ldB(d, nf, kk);
    BARRIER();
    __builtin_amdgcn_s_setprio(1);
#pragma unroll
    for (int mf = 0; mf < 4; mf++)
#pragma unroll
      for (int nf = 2; nf < 4; nf++)
#pragma unroll
        for (int kk = 0; kk < 2; kk++)
          acc[mf][nf] = __builtin_amdgcn_mfma_f32_16x16x32_bf16(af[mf][kk], bfr[nf][kk], acc[mf][nf], 0, 0, 0);
    __builtin_amdgcn_s_setprio(0);
    BARRIER();

    if (kt + 2 < NKT) issueHalf(kt + 2, 2);
#pragma unroll
    for (int mf = 0; mf < 4; mf++)
#pragma unroll
      for (int kk = 0; kk < 2; kk++) af[mf][kk] = ldA(d, mf + 4, kk);
    BARRIER();
    __builtin_amdgcn_s_setprio(1);
#pragma unroll
    for (int mf = 0; mf < 4; mf++)
#pragma unroll
      for (int nf = 0; nf < 2; nf++)
#pragma unroll
        for (int kk = 0; kk < 2; kk++)
          acc[mf + 4][nf] = __builtin_amdgcn_mfma_f32_16x16x32_bf16(af[mf][kk], bfr[nf][kk], acc[mf + 4][nf], 0, 0, 0);
    __builtin_amdgcn_s_setprio(0);
    BARRIER();

    if (kt + 2 < NKT) {
      issueHalf(kt + 2, 0);
      asm volatile("s_waitcnt vmcnt(4)" ::: "memory");
    } else if (kt + 1 < NKT) {
      asm volatile("s_waitcnt vmcnt(0)" ::: "memory");
    }
    BARRIER();
    __builtin_amdgcn_s_setprio(1);
#pragma unroll
    for (int mf = 0; mf < 4; mf++)
#pragma unroll
      for (int nf = 2; nf < 4; nf++)
#pragma unroll
        for (int kk = 0; kk < 2; kk++)
          acc[mf + 4][nf] = __builtin_amdgcn_mfma_f32_16x16x32_bf16(af[mf][kk], bfr[nf][kk], acc[mf + 4][nf], 0, 0, 0);
    __builtin_amdgcn_s_setprio(0);
    BARRIER();
  }

#pragma unroll
  for (int nf = 0; nf < 4; nf++) {
    const int gcol = bn + wc * 64 + nf * 16 + r;
    const float bv = HAS_BIAS ? bias[gcol] : 0.f;
#pragma unroll
    for (int mf = 0; mf < 8; mf++) {
#pragma unroll
      for (int j = 0; j < 4; j++) {
        const int grow = bm + wr * 128 + mf * 16 + 4 * g + j;
        float v = acc[mf][nf][j] + bv;
        if constexpr (OUT_BF16)
          ((__hip_bfloat16*)Cv)[(size_t)grow * ldc + gcol] = __float2bfloat16(v);
        else
          ((float*)Cv)[(size_t)grow * ldc + gcol] = v;
      }
    }
  }
}

// ---------------- GEMM 128^2 (m97 structure, proven r1-r5) -----------------
// C[M][N](ldc) = A[M][K] * B[N][K]^T (+bias). 4 waves, BK=32, 16 KB LDS.
template<bool HAS_BIAS, bool OUT_BF16>
__global__ __launch_bounds__(256)
void gemm_bt(const __hip_bfloat16* __restrict__ A, const __hip_bfloat16* __restrict__ Bm,
             const float* __restrict__ bias, void* __restrict__ Cv,
             int M, int N, int K, int ldc) {
  __shared__ __align__(16) __hip_bfloat16 As[128 * 32];
  __shared__ __align__(16) __hip_bfloat16 Bs[128 * 32];
  const int tid = threadIdx.x;
  const int w = tid >> 6, l = tid & 63;
  const int g = l >> 4, r = l & 15;
  const int wr = w >> 1, wc = w & 1;
  const int bm = blockIdx.x * 128;
  const int bn = blockIdx.y * 128;
  const int lr = l >> 2;        // 0..15: row within a 16-row staging chunk
  const int lc = (l & 3) * 8;   // 0/8/16/24: k-col offset within chunk

  f32x4 acc[4][4];
#pragma unroll
  for (int m = 0; m < 4; m++)
#pragma unroll
    for (int n = 0; n < 4; n++) acc[m][n] = (f32x4){0.f, 0.f, 0.f, 0.f};

  for (int k0 = 0; k0 < K; k0 += 32) {
#pragma unroll
    for (int i = 0; i < 2; i++) {
      const int rb = w * 32 + i * 16;
      gload_lds16(&A[(size_t)(bm + rb + lr) * K + k0 + lc], &As[rb * 32]);
      gload_lds16(&Bm[(size_t)(bn + rb + lr) * K + k0 + lc], &Bs[rb * 32]);
    }
    __syncthreads();
    bf16x8 af[4], bfr[4];
#pragma unroll
    for (int m = 0; m < 4; m++) af[m] = *(const bf16x8*)&As[(wr * 64 + m * 16 + r) * 32 + g * 8];
#pragma unroll
    for (int n = 0; n < 4; n++) bfr[n] = *(const bf16x8*)&Bs[(wc * 64 + n * 16 + r) * 32 + g * 8];
#pragma unroll
    for (int m = 0; m < 4; m++)
#pragma unroll
      for (int n = 0; n < 4; n++)
        acc[m][n] = __builtin_amdgcn_mfma_f32_16x16x32_bf16(af[m], bfr[n], acc[m][n], 0, 0, 0);
    __syncthreads();
  }

#pragma unroll
  for (int m = 0; m < 4; m++) {
#pragma unroll
    for (int n = 0; n < 4; n++) {
      const int gcol = bn + wc * 64 + n * 16 + r;
      const float bv = HAS_BIAS ? bias[gcol] : 0.f;
#pragma unroll
      for (int j = 0; j < 4; j++) {
        const int grow = bm + wr * 64 + m * 16 + 4 * g + j;
        float v = acc[m][n][j] + bv;
        if constexpr (OUT_BF16)
          ((__hip_bfloat16*)Cv)[(size_t)grow * ldc + gcol] = __float2bfloat16(v);
        else
          ((float*)Cv)[(size_t)grow * ldc + gcol] = v;
      }
    }
  }
}

// ---------------- RoPE on Q and K head slots (in-place, bf16, x4 vec) ------
// Q heads additionally scaled by scl2 = (1/sqrt(128))*log2(e).
__global__ __launch_bounds__(256)
void rope_qk(__hip_bfloat16* __restrict__ QKV, const float* __restrict__ cosb,
             const float* __restrict__ sinb) {
  int i = blockIdx.x * 256 + threadIdx.x;   // 2,097,152 threads
  int d = (i & 15) * 4;
  int hh = (i >> 4) & 31;
  int row = i >> 9;
  int cb = (hh < NHQ) ? hh * HD : HID + (hh - NHQ) * HD;
  const float qs = (hh < NHQ) ? 0.12751744055204955f : 1.0f;
  unsigned short* base = (unsigned short*)QKV + (size_t)row * NQKV + cb;
  float4 c = *(const float4*)&cosb[row * HD + d];
  float4 sn = *(const float4*)&sinb[row * HD + d];
  ushort4 u1 = *(const ushort4*)(base + d);
  ushort4 u2 = *(const ushort4*)(base + d + 64);
  float x1[4] = {bf2f(u1.x), bf2f(u1.y), bf2f(u1.z), bf2f(u1.w)};
  float x2[4] = {bf2f(u2.x), bf2f(u2.y), bf2f(u2.z), bf2f(u2.w)};
  float cc[4] = {c.x, c.y, c.z, c.w};
  float ss[4] = {sn.x, sn.y, sn.z, sn.w};
  ushort4 o1, o2;
  o1.x = f2bf((x1[0] * cc[0] - x2[0] * ss[0]) * qs); o2.x = f2bf((x2[0] * cc[0] + x1[0] * ss[0]) * qs);
  o1.y = f2bf((x1[1] * cc[1] - x2[1] * ss[1]) * qs); o2.y = f2bf((x2[1] * cc[1] + x1[1] * ss[1]) * qs);
  o1.z = f2bf((x1[2] * cc[2] - x2[2] * ss[2]) * qs); o2.z = f2bf((x2[2] * cc[2] + x1[2] * ss[2]) * qs);
  o1.w = f2bf((x1[3] * cc[3] - x2[3] * ss[3]) * qs); o2.w = f2bf((x2[3] * cc[3] + x1[3] * ss[3]) * qs);
  *(ushort4*)(base + d) = o1;
  *(ushort4*)(base + d + 64) = o2;
}

// ---------------- V transpose (LDS-tiled, coalesced both sides) ------------
__global__ __launch_bounds__(256)
void v_transpose(const __hip_bfloat16* __restrict__ QKV, __hip_bfloat16* __restrict__ Vt) {
  __shared__ ushort tile[64][136];   // +8 pad
  const int st = blockIdx.x & 31, kv = (blockIdx.x >> 5) & 3, b = blockIdx.x >> 7;
  const int s0 = st * 64;
  const int t = threadIdx.x;
  const int sl = t >> 4, dv = (t & 15) * 8;
  const ushort* src = (const ushort*)QKV + (size_t)(b * SEQ) * NQKV + HID + 512 + kv * HD;
#pragma unroll
  for (int p = 0; p < 4; p++) {
    const int s = s0 + p * 16 + sl;
    *(uint4*)&tile[p * 16 + sl][dv] = *(const uint4*)&src[(size_t)s * NQKV + dv];
  }
  __syncthreads();
  ushort* dst = (ushort*)Vt + (size_t)((b * NKVH + kv) * HD) * SEQ;
#pragma unroll
  for (int it = 0; it < 8; it++) {
    const int idx = it * 256 + t;
    const int d = idx >> 4, sg = idx & 15;
    ushort4 o;
    o.x = tile[sg * 4 + 0][d];
    o.y = tile[sg * 4 + 1][d];
    o.z = tile[sg * 4 + 2][d];
    o.w = tile[sg * 4 + 3][d];
    *(ushort4*)&dst[(size_t)d * SEQ + s0 + sg * 4] = o;
  }
}

// ---------------- Flash attention: 32x32 MFMA, streaming 32-col passes -----
// (r11 structure + r14 LPT grid.) lsum kept per-half; combined once at
// epilogue (al identical across halves since pmax is shfl-shared).
__global__ __launch_bounds__(256, 2)
void attn_fwd(const __hip_bfloat16* __restrict__ QKV, const __hip_bfloat16* __restrict__ Vt,
              __hip_bfloat16* __restrict__ AO) {
  const int head = blockIdx.x >> 1;         // 0..27
  const int b = blockIdx.x & 1;             // 0..1
  const int qb = 15 - blockIdx.y;           // LPT: qb=15 blocks dispatch first
  const int kvh = head / GRP;
  const int tid = threadIdx.x;
  const int w = tid >> 6, l = tid & 63;
  const int q32 = l & 31;                   // lane's q within wave tile
  const int hf = l >> 5;                    // lane half
  const int qw = qb * 128 + w * 32;         // wave's first q row
  const float NEGINF = -__builtin_inff();

  __shared__ __align__(16) __hip_bfloat16 Ks[2][64 * 128];   // 2x16 KB, swizzled
  __shared__ __align__(16) __hip_bfloat16 Vs[2][128 * 64];   // 2x16 KB, swizzled

  const char* Kb = (const char*)(QKV + (size_t)(b * SEQ) * NQKV + HID + kvh * HD);
  const char* Vb = (const char*)(Vt + (size_t)((b * NKVH + kvh) * HD) * SEQ);
  const __hip_bfloat16* Qb = QKV + (size_t)(b * SEQ + qw) * NQKV + head * HD;

  bf16x8 qf[8];
#pragma unroll
  for (int c = 0; c < 8; c++)
    qf[c] = *(const bf16x8*)&Qb[(size_t)q32 * NQKV + c * 16 + 8 * hf];

  f32x16 of[4] = {};
  float mrow = -3e38f, lsum = 0.f;   // lsum = this half's partial sum

  const int ntiles = 2 * qb + 2;

  auto stage = [&](int buf, int kv0) {
#pragma unroll
    for (int p = 0; p < 4; p++) {
      const int row = w * 16 + p * 4 + (l >> 4);      // K tile row (local)
      const int cb = (l & 15) * 16;
      gload_lds16(Kb + (size_t)(kv0 + row) * (NQKV * 2) + (cb ^ ((row & 7) << 4)),
                  (char*)(Ks[buf]) + w * 4096 + p * 1024);
    }
#pragma unroll
    for (int p = 0; p < 4; p++) {
      const int row = w * 32 + p * 8 + (l >> 3);      // V^T tile row (= d)
      const int cb = (l & 7) * 16;
      gload_lds16(Vb + (size_t)row * (SEQ * 2) + (size_t)kv0 * 2 + (cb ^ ((row & 7) << 4)),
                  (char*)(Vs[buf]) + w * 4096 + p * 1024);
    }
  };

  stage(0, 0);
  __syncthreads();

  const int swz = (q32 & 7) << 4;   // row&7 == q32&7 for all our LDS reads
  const int qg = qw + q32;

  for (int t = 0; t < ntiles; t++) {
    const int cur = t & 1;
    if (t + 1 < ntiles) stage(cur ^ 1, t * 64 + 64);  // prefetch under compute

#pragma unroll
    for (int half = 0; half < 2; half++) {
      const int kv0 = t * 64 + half * 32;
      if (kv0 <= qw + 31) {
        // ---- QK^T swapped, 32x32x16 (one 32-col pass); Q pre-scaled
        f32x16 s = {};
        const char* kb = (const char*)(Ks[cur]) + (half * 32 + q32) * 256;
#pragma unroll
        for (int c = 0; c < 8; c++) {
          bf16x8 kf = *(const bf16x8*)(kb + ((c * 32 + 16 * hf) ^ swz));
          s = __builtin_amdgcn_mfma_f32_32x32x16_bf16(kf, qf[c], s, 0, 0, 0);
        }

        // ---- mask + per-lane max
        float pmax = -3e38f;
        if (kv0 + 31 <= qw) {               // interior pass: no mask
#pragma unroll
          for (int j = 0; j < 16; j++) pmax = fmaxf(pmax, s[j]);
        } else {
#pragma unroll
          for (int j = 0; j < 16; j++) {
            const int kvl = (j & 3) + 8 * (j >> 2) + 4 * hf;
            s[j] = (kv0 + kvl <= qg) ? s[j] : NEGINF;
            pmax = fmaxf(pmax, s[j]);
          }
        }
        pmax = fmaxf(pmax, __shfl_xor(pmax, 32));

        // ---- online softmax, defer-max (THR=11.5 in log2 domain)
        float rs = 0.f;
        if (__all(pmax - mrow <= 11.5f)) {
#pragma unroll
          for (int j = 0; j < 16; j++) { float p = exp2f(s[j] - mrow); s[j] = p; rs += p; }
        } else {
          const float nm = fmaxf(mrow, pmax);
          const float al = exp2f(mrow - nm);
          mrow = nm;
#pragma unroll
          for (int j = 0; j < 16; j++) { float p = exp2f(s[j] - nm); s[j] = p; rs += p; }
          lsum *= al;
#pragma unroll
          for (int db = 0; db < 4; db++) of[db] *= al;
        }
        lsum += rs;   // half-partial; combined at epilogue

        // ---- pack P pairs -> u32 words (8 live)
        int wv[8];
#pragma unroll
        for (int k = 0; k < 8; k++)
          wv[k] = (int)((unsigned)f2bf(s[2 * k]) | ((unsigned)f2bf(s[2 * k + 1]) << 16));

        // ---- PV t4=0: pB built transiently; kv local 0..15
        {
          auto ra = __builtin_amdgcn_permlane32_swap(wv[0], wv[2], false, false);
          auto rb = __builtin_amdgcn_permlane32_swap(wv[1], wv[3], false, false);
          union { int4v i; bf16x8 h; } u;
          u.i = (int4v){(int)ra[0], (int)rb[0], (int)ra[1], (int)rb[1]};
          const bf16x8 pB = u.h;
#pragma unroll
          for (int db = 0; db < 4; db++) {
            const char* vp = (const char*)(Vs[cur]) + (db * 32 + q32) * 128;
            bf16x8 vf = *(const bf16x8*)(vp + ((half * 64 + 0 + 16 * hf) ^ swz));
            of[db] = __builtin_amdgcn_mfma_f32_32x32x16_bf16(vf, pB, of[db], 0, 0, 0);
          }
        }
        // ---- PV t4=1: kv local 16..31
        {
          auto rc = __builtin_amdgcn_permlane32_swap(wv[4], wv[6], false, false);
          auto rd = __builtin_amdgcn_permlane32_swap(wv[5], wv[7], false, false);
          union { int4v i; bf16x8 h; } u2;
          u2.i = (int4v){(int)rc[0], (int)rd[0], (int)rc[1], (int)rd[1]};
          const bf16x8 pB = u2.h;
#pragma unroll
          for (int db = 0; db < 4; db++) {
            const char* vp = (const char*)(Vs[cur]) + (db * 32 + q32) * 128;
            bf16x8 vf = *(const bf16x8*)(vp + ((half * 64 + 32 + 16 * hf) ^ swz));
            of[db] = __builtin_amdgcn_mfma_f32_32x32x16_bf16(vf, pB, of[db], 0, 0, 0);
          }
        }
      }
    }
    __syncthreads();   // drains prefetch + guards buffer reuse
  }

  // ---- epilogue: combine half-sums once, then normalize + store
  const float ltot = lsum + __shfl_xor(lsum, 32);
  unsigned short* AOu = (unsigned short*)AO;
  const float inv = 1.0f / ltot;
  const size_t rowb = (size_t)(b * SEQ + qw + q32) * HID + head * HD;
#pragma unroll
  for (int db = 0; db < 4; db++) {
#pragma unroll
    for (int qd = 0; qd < 4; qd++) {
      ushort4 o;
      o.x = f2bf(of[db][4 * qd + 0] * inv);
      o.y = f2bf(of[db][4 * qd + 1] * inv);
      o.z = f2bf(of[db][4 * qd + 2] * inv);
      o.w = f2bf(of[db][4 * qd + 3] * inv);
      *(ushort4*)&AOu[rowb + db * 32 + 8 * qd + 4 * hf] = o;
    }
  }
}

// ---------------------------------------------------------------------------
extern "C" void kernel_launch(void* const* d_in, const int* in_sizes, int n_in,
                              void* d_out, int out_size, void* d_ws, size_t ws_size,
                              hipStream_t stream) {
  const float* hs = (const float*)d_in[0];
  const float* cosb = (const float*)d_in[1];
  const float* sinb = (const float*)d_in[2];
  const float* Wq = (const float*)d_in[3];
  const float* bq = (const float*)d_in[4];
  const float* Wk = (const float*)d_in[5];
  const float* bk = (const float*)d_in[6];
  const float* Wv = (const float*)d_in[7];
  const float* bv = (const float*)d_in[8];
  const float* Wo = (const float*)d_in[9];

  char* ws = (char*)d_ws;
  __hip_bfloat16* Xb = (__hip_bfloat16*)(ws);
  __hip_bfloat16* Wcat = (__hip_bfloat16*)(ws + 29360128);
  float* bcat = (float*)(ws + 62390272);
  __hip_bfloat16* QKVb = (__hip_bfloat16*)(ws + 62408704);
  __hip_bfloat16* Vt = (__hip_bfloat16*)(ws + 100157440);
  __hip_bfloat16* AOb = Xb;    // X dead after projections
  __hip_bfloat16* Wob = Wcat;  // Wq/Wk rows dead after QK GEMM

  // Fused conversions (X, Wq, Wk, Wv) + bias concat
  cvt_fused<<<30464, 256, 0, stream>>>(hs, Wq, Wk, Wv, Xb, Wcat);
  concat_bias<<<18, 256, 0, stream>>>(bq, bk, bv, bcat);

  // QK projection: [4096 x 4096] -> QKVb cols 0..4095. 256 blocks = 1 round.
  gemm256<true, true><<<256, 512, 0, stream>>>(Xb, Wcat, bcat, QKVb,
                                               4096, 4096, HID, 16, NQKV);

  // V projection: [4096 x 512] on 128^2 tiles -> 128 blocks.
  dim3 gv(32, 4);
  gemm_bt<true, true><<<gv, 256, 0, stream>>>(Xb, Wcat + (size_t)4096 * 3584,
                                              bcat + 4096, QKVb + 4096,
                                              4096, 512, HID, NQKV);

  // RoPE on Q + K head slots (in place; Q pre-scaled by scl2)
  rope_qk<<<8192, 256, 0, stream>>>(QKVb, cosb, sinb);

  // V transpose (LDS-tiled, coalesced)
  v_transpose<<<256, 256, 0, stream>>>(QKVb, Vt);

  // Wo conversion (into the now-dead Wq/Wk rows of Wcat)
  cvt_f32_bf16<<<12544, 256, 0, stream>>>(Wo, Wob, 3211264);

  // Flash attention: 128-row Q blocks, 4 waves x 32 rows, 64-col KV tiles.
  dim3 ga(56, 16);
  attn_fwd<<<ga, 256, 0, stream>>>(QKVb, Vt, AOb);

  // O projection -> f32 out (224 blocks, one round)
  gemm256<false, false><<<224, 512, 0, stream>>>(AOb, Wob, nullptr, d_out,
                                                 4096, HID, HID, 16, HID);
}

// Round 18
// 465.016 us; speedup vs baseline: 3.6019x; 1.0055x over previous
//
#include <hip/hip_runtime.h>
#include <hip/hip_bf16.h>

// Qwen2 attention layer, MI355X/gfx950.
// B=2 S=2048 HID=3584 NH=28 NKV=4 D=128, causal, GQA groups=7.
// Round 18 = round 17 (467.6 us) + three safe cuts:
//  - T5 s_setprio(1) around attn MFMA clusters (2 independent blocks/CU at
//    different phases -> scheduler can favor MFMA waves; m191: +4-7% attn).
//  - attn: final-tile __syncthreads skipped (no prefetch/LDS reuse after).
//  - rope_qk + v_transpose merged into one launch (disjoint QKVb regions).
//
// Workspace layout (bytes), total ~99.5 MB:
//   Xb    @ 0          29,360,128  (B*S x HID bf16)      -> reused as AOb
//   Wcat  @ 29,360,128 33,030,144  (4608 x 3584 bf16)    -> reused as Wo-bf16
//   bcat  @ 62,390,272 18,432      (4608 f32)
//   QKVb  @ 62,408,704 37,748,736  (B*S x 4608 bf16)
//   Vt    @ 100,157,440 4,194,304  (B*NKV*128 x S bf16)

#define HID   3584
#define NHQ   28
#define NKVH  4
#define HD    128
#define SEQ   2048
#define NQKV  4608
#define GRP   7

typedef __attribute__((ext_vector_type(8))) short bf16x8;
typedef __attribute__((ext_vector_type(4))) float f32x4;
typedef __attribute__((ext_vector_type(16))) float f32x16;
typedef __attribute__((ext_vector_type(4))) int int4v;

#define BARRIER() asm volatile("s_barrier" ::: "memory")

__device__ __forceinline__ void gload_lds16(const void* g, void* l) {
  __builtin_amdgcn_global_load_lds(
      (const __attribute__((address_space(1))) void*)g,
      (__attribute__((address_space(3))) void*)l, 16, 0, 0);
}

__device__ __forceinline__ unsigned short f2bf(float f) {
  __hip_bfloat16 h = __float2bfloat16(f);
  return *reinterpret_cast<unsigned short*>(&h);
}

__device__ __forceinline__ float bf2f(unsigned short u) {
  __hip_bfloat16 h = *reinterpret_cast<__hip_bfloat16*>(&u);
  return __bfloat162float(h);
}

// ---------------- fused f32 -> bf16 conversion (X, Wq, Wk, Wv) -------------
__global__ __launch_bounds__(256)
void cvt_fused(const float* __restrict__ X, const float* __restrict__ Wq,
               const float* __restrict__ Wk, const float* __restrict__ Wv,
               __hip_bfloat16* __restrict__ Xb, __hip_bfloat16* __restrict__ Wcat) {
  int i = blockIdx.x * 256 + threadIdx.x;   // 0 .. 7,798,783
  const float* src;
  __hip_bfloat16* dst;
  int off;
  if (i < 3670016)      { src = X;  dst = Xb;   off = i; }
  else if (i < 6881280) { src = Wq; dst = Wcat; off = i - 3670016; }
  else if (i < 7340032) { src = Wk; dst = Wcat + (size_t)3584 * 3584; off = i - 6881280; }
  else                  { src = Wv; dst = Wcat + (size_t)4096 * 3584; off = i - 7340032; }
  float4 v = ((const float4*)src)[off];
  ushort4 o;
  o.x = f2bf(v.x); o.y = f2bf(v.y); o.z = f2bf(v.z); o.w = f2bf(v.w);
  ((ushort4*)dst)[off] = o;
}

__global__ __launch_bounds__(256)
void cvt_f32_bf16(const float* __restrict__ src, __hip_bfloat16* __restrict__ dst, int n4) {
  int i = blockIdx.x * 256 + threadIdx.x;
  if (i >= n4) return;
  float4 v = ((const float4*)src)[i];
  ushort4 o;
  o.x = f2bf(v.x); o.y = f2bf(v.y); o.z = f2bf(v.z); o.w = f2bf(v.w);
  ((ushort4*)dst)[i] = o;
}

__global__ __launch_bounds__(256)
void concat_bias(const float* __restrict__ bq, const float* __restrict__ bk,
                 const float* __restrict__ bv, float* __restrict__ out) {
  int i = blockIdx.x * 256 + threadIdx.x;
  if (i < HID) out[i] = bq[i];
  else if (i < HID + 512) out[i] = bk[i - HID];
  else if (i < NQKV) out[i] = bv[i - HID - 512];
}

// ---------------- GEMM 256^2: C[M][N](ldc) = A[M][K] * B[N][K]^T (+bias) ---
template<bool HAS_BIAS, bool OUT_BF16>
__global__ __launch_bounds__(512, 2)
void gemm256(const __hip_bfloat16* __restrict__ A, const __hip_bfloat16* __restrict__ Bm,
             const float* __restrict__ bias, void* __restrict__ Cv,
             int M, int N, int K, int nmt, int ldc) {
  __shared__ __align__(16) char lds[131072];
  const int tid = threadIdx.x;
  const int w = tid >> 6, l = tid & 63;
  const int g = l >> 4, r = l & 15;
  const int wr = w >> 2, wc = w & 3;

  // bijective XCD swizzle (nwg % 8 == 0 for all our grids)
  const int nwg = gridDim.x;
  const int qq = nwg >> 3, r8 = nwg & 7;
  const int xcd = blockIdx.x & 7, idx = blockIdx.x >> 3;
  const int wgid = (xcd < r8 ? xcd * (qq + 1) : r8 * (qq + 1) + (xcd - r8) * qq) + idx;
  const int bm = (wgid % nmt) * 256, bn = (wgid / nmt) * 256;

  const int NKT = K >> 6;
  const size_t Kb2 = (size_t)K * 2;
  const int swz = (r & 7) << 4;

  auto issueHalf = [&](int kt, int h) {
    const char* src = (h < 2) ? (const char*)A : (const char*)Bm;
    const int rbase = (h < 2) ? bm : bn;
    char* reg = lds + (kt & 1) * 65536 + ((h < 2) ? 0 : 32768);
#pragma unroll
    for (int i = 0; i < 2; ++i) {
      const int lrow = (h & 1) * 128 + w * 16 + i * 8;   // wave-uniform dest row
      const int row = lrow + (l >> 3);                    // per-lane source row
      const int cb = (l & 7) * 16;
      gload_lds16(src + (size_t)(rbase + row) * Kb2 + (size_t)kt * 128 + (cb ^ ((row & 7) << 4)),
                  reg + lrow * 128);
    }
  };

  auto ldA = [&](int d, int mf, int kk) -> bf16x8 {
    const int row = wr * 128 + mf * 16 + r;
    return *(const bf16x8*)(lds + d * 65536 + row * 128 + ((kk * 64 + g * 16) ^ swz));
  };
  auto ldB = [&](int d, int nf, int kk) -> bf16x8 {
    const int row = wc * 64 + nf * 16 + r;
    return *(const bf16x8*)(lds + d * 65536 + 32768 + row * 128 + ((kk * 64 + g * 16) ^ swz));
  };

  f32x4 acc[8][4];
#pragma unroll
  for (int m = 0; m < 8; m++)
#pragma unroll
    for (int n = 0; n < 4; n++) acc[m][n] = (f32x4){0.f, 0.f, 0.f, 0.f};

#pragma unroll
  for (int h = 0; h < 4; ++h) issueHalf(0, h);
#pragma unroll
  for (int h = 0; h < 4; ++h) issueHalf(1, h);
  asm volatile("s_waitcnt vmcnt(8)" ::: "memory");
  BARRIER();

  bf16x8 af[4][2], bfr[4][2];

#pragma unroll 1
  for (int kt = 0; kt < NKT; ++kt) {
    const int d = kt & 1;

    if (kt >= 1 && kt + 1 < NKT) { issueHalf(kt + 1, 1); issueHalf(kt + 1, 3); }
#pragma unroll
    for (int mf = 0; mf < 4; mf++)
#pragma unroll
      for (int kk = 0; kk < 2; kk++) af[mf][kk] = ldA(d, mf, kk);
#pragma unroll
    for (int nf = 0; nf < 2; nf++)
#pragma unroll
      for (int kk = 0; kk < 2; kk++) bfr[nf][kk] = ldB(d, nf, kk);
    BARRIER();
    __builtin_amdgcn_s_setprio(1);
#pragma unroll
    for (int mf = 0; mf < 4; mf++)
#pragma unroll
      for (int nf = 0; nf < 2; nf++)
#pragma unroll
        for (int kk = 0; kk < 2; kk++)
          acc[mf][nf] = __builtin_amdgcn_mfma_f32_16x16x32_bf16(af[mf][kk], bfr[nf][kk], acc[mf][nf], 0, 0, 0);
    __builtin_amdgcn_s_setprio(0);
    BARRIER();

#pragma unroll
    for (int nf = 2; nf < 4; nf++)
#pragma unroll
      for (int kk = 0; kk < 2; kk++) bfr[nf][kk] = ldB(d, nf, kk);
    BARRIER();
    __builtin_amdgcn_s_setprio(1);
#pragma unroll
    for (int mf = 0; mf < 4; mf++)
#pragma unroll
      for (int nf = 2; nf < 4; nf++)
#pragma unroll
        for (int kk = 0; kk < 2; kk++)
          acc[mf][nf] = __builtin_amdgcn_mfma_f32_16x16x32_bf16(af[mf][kk], bfr[nf][kk], acc[mf][nf], 0, 0, 0);
    __builtin_amdgcn_s_setprio(0);
    BARRIER();

    if (kt + 2 < NKT) issueHalf(kt + 2, 2);
#pragma unroll
    for (int mf = 0; mf < 4; mf++)
#pragma unroll
      for (int kk = 0; kk < 2; kk++) af[mf][kk] = ldA(d, mf + 4, kk);
    BARRIER();
    __builtin_amdgcn_s_setprio(1);
#pragma unroll
    for (int mf = 0; mf < 4; mf++)
#pragma unroll
      for (int nf = 0; nf < 2; nf++)
#pragma unroll
        for (int kk = 0; kk < 2; kk++)
          acc[mf + 4][nf] = __builtin_amdgcn_mfma_f32_16x16x32_bf16(af[mf][kk], bfr[nf][kk], acc[mf + 4][nf], 0, 0, 0);
    __builtin_amdgcn_s_setprio(0);
    BARRIER();

    if (kt + 2 < NKT) {
      issueHalf(kt + 2, 0);
      asm volatile("s_waitcnt vmcnt(4)" ::: "memory");
    } else if (kt + 1 < NKT) {
      asm volatile("s_waitcnt vmcnt(0)" ::: "memory");
    }
    BARRIER();
    __builtin_amdgcn_s_setprio(1);
#pragma unroll
    for (int mf = 0; mf < 4; mf++)
#pragma unroll
      for (int nf = 2; nf < 4; nf++)
#pragma unroll
        for (int kk = 0; kk < 2; kk++)
          acc[mf + 4][nf] = __builtin_amdgcn_mfma_f32_16x16x32_bf16(af[mf][kk], bfr[nf][kk], acc[mf + 4][nf], 0, 0, 0);
    __builtin_amdgcn_s_setprio(0);
    BARRIER();
  }

#pragma unroll
  for (int nf = 0; nf < 4; nf++) {
    const int gcol = bn + wc * 64 + nf * 16 + r;
    const float bv = HAS_BIAS ? bias[gcol] : 0.f;
#pragma unroll
    for (int mf = 0; mf < 8; mf++) {
#pragma unroll
      for (int j = 0; j < 4; j++) {
        const int grow = bm + wr * 128 + mf * 16 + 4 * g + j;
        float v = acc[mf][nf][j] + bv;
        if constexpr (OUT_BF16)
          ((__hip_bfloat16*)Cv)[(size_t)grow * ldc + gcol] = __float2bfloat16(v);
        else
          ((float*)Cv)[(size_t)grow * ldc + gcol] = v;
      }
    }
  }
}

// ---------------- GEMM 128^2 (m97 structure) -------------------------------
template<bool HAS_BIAS, bool OUT_BF16>
__global__ __launch_bounds__(256)
void gemm_bt(const __hip_bfloat16* __restrict__ A, const __hip_bfloat16* __restrict__ Bm,
             const float* __restrict__ bias, void* __restrict__ Cv,
             int M, int N, int K, int ldc) {
  __shared__ __align__(16) __hip_bfloat16 As[128 * 32];
  __shared__ __align__(16) __hip_bfloat16 Bs[128 * 32];
  const int tid = threadIdx.x;
  const int w = tid >> 6, l = tid & 63;
  const int g = l >> 4, r = l & 15;
  const int wr = w >> 1, wc = w & 1;
  const int bm = blockIdx.x * 128;
  const int bn = blockIdx.y * 128;
  const int lr = l >> 2;
  const int lc = (l & 3) * 8;

  f32x4 acc[4][4];
#pragma unroll
  for (int m = 0; m < 4; m++)
#pragma unroll
    for (int n = 0; n < 4; n++) acc[m][n] = (f32x4){0.f, 0.f, 0.f, 0.f};

  for (int k0 = 0; k0 < K; k0 += 32) {
#pragma unroll
    for (int i = 0; i < 2; i++) {
      const int rb = w * 32 + i * 16;
      gload_lds16(&A[(size_t)(bm + rb + lr) * K + k0 + lc], &As[rb * 32]);
      gload_lds16(&Bm[(size_t)(bn + rb + lr) * K + k0 + lc], &Bs[rb * 32]);
    }
    __syncthreads();
    bf16x8 af[4], bfr[4];
#pragma unroll
    for (int m = 0; m < 4; m++) af[m] = *(const bf16x8*)&As[(wr * 64 + m * 16 + r) * 32 + g * 8];
#pragma unroll
    for (int n = 0; n < 4; n++) bfr[n] = *(const bf16x8*)&Bs[(wc * 64 + n * 16 + r) * 32 + g * 8];
#pragma unroll
    for (int m = 0; m < 4; m++)
#pragma unroll
      for (int n = 0; n < 4; n++)
        acc[m][n] = __builtin_amdgcn_mfma_f32_16x16x32_bf16(af[m], bfr[n], acc[m][n], 0, 0, 0);
    __syncthreads();
  }

#pragma unroll
  for (int m = 0; m < 4; m++) {
#pragma unroll
    for (int n = 0; n < 4; n++) {
      const int gcol = bn + wc * 64 + n * 16 + r;
      const float bv = HAS_BIAS ? bias[gcol] : 0.f;
#pragma unroll
      for (int j = 0; j < 4; j++) {
        const int grow = bm + wr * 64 + m * 16 + 4 * g + j;
        float v = acc[m][n][j] + bv;
        if constexpr (OUT_BF16)
          ((__hip_bfloat16*)Cv)[(size_t)grow * ldc + gcol] = __float2bfloat16(v);
        else
          ((float*)Cv)[(size_t)grow * ldc + gcol] = v;
      }
    }
  }
}

// ---------------- RoPE (Q scaled by scl2) + V transpose, fused -------------
// Blocks 0..8191: rope. Blocks 8192..8447: V transpose (disjoint regions).
__global__ __launch_bounds__(256)
void rope_vt(__hip_bfloat16* __restrict__ QKV, const float* __restrict__ cosb,
             const float* __restrict__ sinb, __hip_bfloat16* __restrict__ Vt) {
  if (blockIdx.x < 8192) {
    int i = blockIdx.x * 256 + threadIdx.x;
    int d = (i & 15) * 4;
    int hh = (i >> 4) & 31;
    int row = i >> 9;
    int cb = (hh < NHQ) ? hh * HD : HID + (hh - NHQ) * HD;
    const float qs = (hh < NHQ) ? 0.12751744055204955f : 1.0f;
    unsigned short* base = (unsigned short*)QKV + (size_t)row * NQKV + cb;
    float4 c = *(const float4*)&cosb[row * HD + d];
    float4 sn = *(const float4*)&sinb[row * HD + d];
    ushort4 u1 = *(const ushort4*)(base + d);
    ushort4 u2 = *(const ushort4*)(base + d + 64);
    float x1[4] = {bf2f(u1.x), bf2f(u1.y), bf2f(u1.z), bf2f(u1.w)};
    float x2[4] = {bf2f(u2.x), bf2f(u2.y), bf2f(u2.z), bf2f(u2.w)};
    float cc[4] = {c.x, c.y, c.z, c.w};
    float ss[4] = {sn.x, sn.y, sn.z, sn.w};
    ushort4 o1, o2;
    o1.x = f2bf((x1[0] * cc[0] - x2[0] * ss[0]) * qs); o2.x = f2bf((x2[0] * cc[0] + x1[0] * ss[0]) * qs);
    o1.y = f2bf((x1[1] * cc[1] - x2[1] * ss[1]) * qs); o2.y = f2bf((x2[1] * cc[1] + x1[1] * ss[1]) * qs);
    o1.z = f2bf((x1[2] * cc[2] - x2[2] * ss[2]) * qs); o2.z = f2bf((x2[2] * cc[2] + x1[2] * ss[2]) * qs);
    o1.w = f2bf((x1[3] * cc[3] - x2[3] * ss[3]) * qs); o2.w = f2bf((x2[3] * cc[3] + x1[3] * ss[3]) * qs);
    *(ushort4*)(base + d) = o1;
    *(ushort4*)(base + d + 64) = o2;
  } else {
    __shared__ ushort tile[64][136];
    const int bx = blockIdx.x - 8192;
    const int st = bx & 31, kv = (bx >> 5) & 3, b = bx >> 7;
    const int s0 = st * 64;
    const int t = threadIdx.x;
    const int sl = t >> 4, dv = (t & 15) * 8;
    const ushort* src = (const ushort*)QKV + (size_t)(b * SEQ) * NQKV + HID + 512 + kv * HD;
#pragma unroll
    for (int p = 0; p < 4; p++) {
      const int s = s0 + p * 16 + sl;
      *(uint4*)&tile[p * 16 + sl][dv] = *(const uint4*)&src[(size_t)s * NQKV + dv];
    }
    __syncthreads();
    ushort* dst = (ushort*)Vt + (size_t)((b * NKVH + kv) * HD) * SEQ;
#pragma unroll
    for (int it = 0; it < 8; it++) {
      const int idx = it * 256 + t;
      const int d = idx >> 4, sg = idx & 15;
      ushort4 o;
      o.x = tile[sg * 4 + 0][d];
      o.y = tile[sg * 4 + 1][d];
      o.z = tile[sg * 4 + 2][d];
      o.w = tile[sg * 4 + 3][d];
      *(ushort4*)&dst[(size_t)d * SEQ + s0 + sg * 4] = o;
    }
  }
}

// ---------------- Flash attention: 32x32 MFMA, streaming 32-col passes -----
// r17 structure + T5 setprio around MFMA clusters + final-barrier skip.
__global__ __launch_bounds__(256, 2)
void attn_fwd(const __hip_bfloat16* __restrict__ QKV, const __hip_bfloat16* __restrict__ Vt,
              __hip_bfloat16* __restrict__ AO) {
  const int head = blockIdx.x >> 1;
  const int b = blockIdx.x & 1;
  const int qb = 15 - blockIdx.y;           // LPT
  const int kvh = head / GRP;
  const int tid = threadIdx.x;
  const int w = tid >> 6, l = tid & 63;
  const int q32 = l & 31;
  const int hf = l >> 5;
  const int qw = qb * 128 + w * 32;
  const float NEGINF = -__builtin_inff();

  __shared__ __align__(16) __hip_bfloat16 Ks[2][64 * 128];
  __shared__ __align__(16) __hip_bfloat16 Vs[2][128 * 64];

  const char* Kb = (const char*)(QKV + (size_t)(b * SEQ) * NQKV + HID + kvh * HD);
  const char* Vb = (const char*)(Vt + (size_t)((b * NKVH + kvh) * HD) * SEQ);
  const __hip_bfloat16* Qb = QKV + (size_t)(b * SEQ + qw) * NQKV + head * HD;

  bf16x8 qf[8];
#pragma unroll
  for (int c = 0; c < 8; c++)
    qf[c] = *(const bf16x8*)&Qb[(size_t)q32 * NQKV + c * 16 + 8 * hf];

  f32x16 of[4] = {};
  float mrow = -3e38f, lsum = 0.f;   // half-partial lsum

  const int ntiles = 2 * qb + 2;

  auto stage = [&](int buf, int kv0) {
#pragma unroll
    for (int p = 0; p < 4; p++) {
      const int row = w * 16 + p * 4 + (l >> 4);
      const int cb = (l & 15) * 16;
      gload_lds16(Kb + (size_t)(kv0 + row) * (NQKV * 2) + (cb ^ ((row & 7) << 4)),
                  (char*)(Ks[buf]) + w * 4096 + p * 1024);
    }
#pragma unroll
    for (int p = 0; p < 4; p++) {
      const int row = w * 32 + p * 8 + (l >> 3);
      const int cb = (l & 7) * 16;
      gload_lds16(Vb + (size_t)row * (SEQ * 2) + (size_t)kv0 * 2 + (cb ^ ((row & 7) << 4)),
                  (char*)(Vs[buf]) + w * 4096 + p * 1024);
    }
  };

  stage(0, 0);
  __syncthreads();

  const int swz = (q32 & 7) << 4;
  const int qg = qw + q32;

  for (int t = 0; t < ntiles; t++) {
    const int cur = t & 1;
    if (t + 1 < ntiles) stage(cur ^ 1, t * 64 + 64);

#pragma unroll
    for (int half = 0; half < 2; half++) {
      const int kv0 = t * 64 + half * 32;
      if (kv0 <= qw + 31) {
        // ---- QK^T swapped (Q pre-scaled); setprio for MFMA cluster
        f32x16 s = {};
        const char* kb = (const char*)(Ks[cur]) + (half * 32 + q32) * 256;
        __builtin_amdgcn_s_setprio(1);
#pragma unroll
        for (int c = 0; c < 8; c++) {
          bf16x8 kf = *(const bf16x8*)(kb + ((c * 32 + 16 * hf) ^ swz));
          s = __builtin_amdgcn_mfma_f32_32x32x16_bf16(kf, qf[c], s, 0, 0, 0);
        }
        __builtin_amdgcn_s_setprio(0);

        // ---- mask + per-lane max
        float pmax = -3e38f;
        if (kv0 + 31 <= qw) {
#pragma unroll
          for (int j = 0; j < 16; j++) pmax = fmaxf(pmax, s[j]);
        } else {
#pragma unroll
          for (int j = 0; j < 16; j++) {
            const int kvl = (j & 3) + 8 * (j >> 2) + 4 * hf;
            s[j] = (kv0 + kvl <= qg) ? s[j] : NEGINF;
            pmax = fmaxf(pmax, s[j]);
          }
        }
        pmax = fmaxf(pmax, __shfl_xor(pmax, 32));

        // ---- online softmax, defer-max (THR=11.5, log2 domain)
        float rs = 0.f;
        if (__all(pmax - mrow <= 11.5f)) {
#pragma unroll
          for (int j = 0; j < 16; j++) { float p = exp2f(s[j] - mrow); s[j] = p; rs += p; }
        } else {
          const float nm = fmaxf(mrow, pmax);
          const float al = exp2f(mrow - nm);
          mrow = nm;
#pragma unroll
          for (int j = 0; j < 16; j++) { float p = exp2f(s[j] - nm); s[j] = p; rs += p; }
          lsum *= al;
#pragma unroll
          for (int db = 0; db < 4; db++) of[db] *= al;
        }
        lsum += rs;

        // ---- pack P pairs -> u32 words
        int wv[8];
#pragma unroll
        for (int k = 0; k < 8; k++)
          wv[k] = (int)((unsigned)f2bf(s[2 * k]) | ((unsigned)f2bf(s[2 * k + 1]) << 16));

        // ---- PV t4=0
        {
          auto ra = __builtin_amdgcn_permlane32_swap(wv[0], wv[2], false, false);
          auto rb = __builtin_amdgcn_permlane32_swap(wv[1], wv[3], false, false);
          union { int4v i; bf16x8 h; } u;
          u.i = (int4v){(int)ra[0], (int)rb[0], (int)ra[1], (int)rb[1]};
          const bf16x8 pB = u.h;
          __builtin_amdgcn_s_setprio(1);
#pragma unroll
          for (int db = 0; db < 4; db++) {
            const char* vp = (const char*)(Vs[cur]) + (db * 32 + q32) * 128;
            bf16x8 vf = *(const bf16x8*)(vp + ((half * 64 + 0 + 16 * hf) ^ swz));
            of[db] = __builtin_amdgcn_mfma_f32_32x32x16_bf16(vf, pB, of[db], 0, 0, 0);
          }
          __builtin_amdgcn_s_setprio(0);
        }
        // ---- PV t4=1
        {
          auto rc = __builtin_amdgcn_permlane32_swap(wv[4], wv[6], false, false);
          auto rd = __builtin_amdgcn_permlane32_swap(wv[5], wv[7], false, false);
          union { int4v i; bf16x8 h; } u2;
          u2.i = (int4v){(int)rc[0], (int)rd[0], (int)rc[1], (int)rd[1]};
          const bf16x8 pB = u2.h;
          __builtin_amdgcn_s_setprio(1);
#pragma unroll
          for (int db = 0; db < 4; db++) {
            const char* vp = (const char*)(Vs[cur]) + (db * 32 + q32) * 128;
            bf16x8 vf = *(const bf16x8*)(vp + ((half * 64 + 32 + 16 * hf) ^ swz));
            of[db] = __builtin_amdgcn_mfma_f32_32x32x16_bf16(vf, pB, of[db], 0, 0, 0);
          }
          __builtin_amdgcn_s_setprio(0);
        }
      }
    }
    if (t + 1 < ntiles) __syncthreads();   // skip after last tile (no reuse)
  }

  // ---- epilogue: combine half-sums, normalize, store
  const float ltot = lsum + __shfl_xor(lsum, 32);
  unsigned short* AOu = (unsigned short*)AO;
  const float inv = 1.0f / ltot;
  const size_t rowb = (size_t)(b * SEQ + qw + q32) * HID + head * HD;
#pragma unroll
  for (int db = 0; db < 4; db++) {
#pragma unroll
    for (int qd = 0; qd < 4; qd++) {
      ushort4 o;
      o.x = f2bf(of[db][4 * qd + 0] * inv);
      o.y = f2bf(of[db][4 * qd + 1] * inv);
      o.z = f2bf(of[db][4 * qd + 2] * inv);
      o.w = f2bf(of[db][4 * qd + 3] * inv);
      *(ushort4*)&AOu[rowb + db * 32 + 8 * qd + 4 * hf] = o;
    }
  }
}

// ---------------------------------------------------------------------------
extern "C" void kernel_launch(void* const* d_in, const int* in_sizes, int n_in,
                              void* d_out, int out_size, void* d_ws, size_t ws_size,
                              hipStream_t stream) {
  const float* hs = (const float*)d_in[0];
  const float* cosb = (const float*)d_in[1];
  const float* sinb = (const float*)d_in[2];
  const float* Wq = (const float*)d_in[3];
  const float* bq = (const float*)d_in[4];
  const float* Wk = (const float*)d_in[5];
  const float* bk = (const float*)d_in[6];
  const float* Wv = (const float*)d_in[7];
  const float* bv = (const float*)d_in[8];
  const float* Wo = (const float*)d_in[9];

  char* ws = (char*)d_ws;
  __hip_bfloat16* Xb = (__hip_bfloat16*)(ws);
  __hip_bfloat16* Wcat = (__hip_bfloat16*)(ws + 29360128);
  float* bcat = (float*)(ws + 62390272);
  __hip_bfloat16* QKVb = (__hip_bfloat16*)(ws + 62408704);
  __hip_bfloat16* Vt = (__hip_bfloat16*)(ws + 100157440);
  __hip_bfloat16* AOb = Xb;    // X dead after projections
  __hip_bfloat16* Wob = Wcat;  // Wq/Wk rows dead after QK GEMM

  // Fused conversions (X, Wq, Wk, Wv) + bias concat
  cvt_fused<<<30464, 256, 0, stream>>>(hs, Wq, Wk, Wv, Xb, Wcat);
  concat_bias<<<18, 256, 0, stream>>>(bq, bk, bv, bcat);

  // QK projection: [4096 x 4096] -> QKVb cols 0..4095. 256 blocks = 1 round.
  gemm256<true, true><<<256, 512, 0, stream>>>(Xb, Wcat, bcat, QKVb,
                                               4096, 4096, HID, 16, NQKV);

  // V projection: [4096 x 512] on 128^2 tiles -> 128 blocks.
  dim3 gv(32, 4);
  gemm_bt<true, true><<<gv, 256, 0, stream>>>(Xb, Wcat + (size_t)4096 * 3584,
                                              bcat + 4096, QKVb + 4096,
                                              4096, 512, HID, NQKV);

  // RoPE (Q pre-scaled) + V transpose, fused launch
  rope_vt<<<8448, 256, 0, stream>>>(QKVb, cosb, sinb, Vt);

  // Wo conversion (into the now-dead Wq/Wk rows of Wcat)
  cvt_f32_bf16<<<12544, 256, 0, stream>>>(Wo, Wob, 3211264);

  // Flash attention
  dim3 ga(56, 16);
  attn_fwd<<<ga, 256, 0, stream>>>(QKVb, Vt, AOb);

  // O projection -> f32 out (224 blocks, one round)
  gemm256<false, false><<<224, 512, 0, stream>>>(AOb, Wob, nullptr, d_out,
                                                 4096, HID, HID, 16, HID);
}

// Round 19
// 457.113 us; speedup vs baseline: 3.6642x; 1.0173x over previous
//
#include <hip/hip_runtime.h>
#include <hip/hip_bf16.h>

// Qwen2 attention layer, MI355X/gfx950.
// B=2 S=2048 HID=3584 NH=28 NKV=4 D=128, causal, GQA groups=7.
// Round 19 = round 18 (465.0 us) + launch fusion + O-proj L2 mapping:
//  - gemm256 wgid mapping is now n-fastest (bn = wgid%nnt): each XCD's
//    contiguous chunk covers whole m-rows -> A panels L2-resident.
//  - concat_bias folded into cvt_fused; Wo conversion folded into rope_vt.
//
// Workspace layout (bytes), total ~99.5 MB:
//   Xb    @ 0          29,360,128  (B*S x HID bf16)      -> reused as AOb
//   Wcat  @ 29,360,128 33,030,144  (4608 x 3584 bf16)    -> reused as Wo-bf16
//   bcat  @ 62,390,272 18,432      (4608 f32)
//   QKVb  @ 62,408,704 37,748,736  (B*S x 4608 bf16)
//   Vt    @ 100,157,440 4,194,304  (B*NKV*128 x S bf16)

#define HID   3584
#define NHQ   28
#define NKVH  4
#define HD    128
#define SEQ   2048
#define NQKV  4608
#define GRP   7

typedef __attribute__((ext_vector_type(8))) short bf16x8;
typedef __attribute__((ext_vector_type(4))) float f32x4;
typedef __attribute__((ext_vector_type(16))) float f32x16;
typedef __attribute__((ext_vector_type(4))) int int4v;

#define BARRIER() asm volatile("s_barrier" ::: "memory")

__device__ __forceinline__ void gload_lds16(const void* g, void* l) {
  __builtin_amdgcn_global_load_lds(
      (const __attribute__((address_space(1))) void*)g,
      (__attribute__((address_space(3))) void*)l, 16, 0, 0);
}

__device__ __forceinline__ unsigned short f2bf(float f) {
  __hip_bfloat16 h = __float2bfloat16(f);
  return *reinterpret_cast<unsigned short*>(&h);
}

__device__ __forceinline__ float bf2f(unsigned short u) {
  __hip_bfloat16 h = *reinterpret_cast<__hip_bfloat16*>(&u);
  return __bfloat162float(h);
}

// ------ fused f32->bf16 conversion (X, Wq, Wk, Wv) + bias concat -----------
__global__ __launch_bounds__(256)
void cvt_fused(const float* __restrict__ X, const float* __restrict__ Wq,
               const float* __restrict__ Wk, const float* __restrict__ Wv,
               const float* __restrict__ bq, const float* __restrict__ bk,
               const float* __restrict__ bv,
               __hip_bfloat16* __restrict__ Xb, __hip_bfloat16* __restrict__ Wcat,
               float* __restrict__ bcat) {
  if (blockIdx.x >= 30464) {   // bias tail: 18 blocks
    int i = (blockIdx.x - 30464) * 256 + threadIdx.x;
    if (i < HID) bcat[i] = bq[i];
    else if (i < HID + 512) bcat[i] = bk[i - HID];
    else if (i < NQKV) bcat[i] = bv[i - HID - 512];
    return;
  }
  int i = blockIdx.x * 256 + threadIdx.x;   // 0 .. 7,798,783 (f32x4 units)
  const float* src;
  __hip_bfloat16* dst;
  int off;
  if (i < 3670016)      { src = X;  dst = Xb;   off = i; }
  else if (i < 6881280) { src = Wq; dst = Wcat; off = i - 3670016; }
  else if (i < 7340032) { src = Wk; dst = Wcat + (size_t)3584 * 3584; off = i - 6881280; }
  else                  { src = Wv; dst = Wcat + (size_t)4096 * 3584; off = i - 7340032; }
  float4 v = ((const float4*)src)[off];
  ushort4 o;
  o.x = f2bf(v.x); o.y = f2bf(v.y); o.z = f2bf(v.z); o.w = f2bf(v.w);
  ((ushort4*)dst)[off] = o;
}

// ---------------- GEMM 256^2: C[M][N](ldc) = A[M][K] * B[N][K]^T (+bias) ---
// n-fastest wgid mapping: bn = wgid%nnt, bm = wgid/nnt -> each XCD chunk
// covers whole m-rows; A panels stay L2-resident.
template<bool HAS_BIAS, bool OUT_BF16>
__global__ __launch_bounds__(512, 2)
void gemm256(const __hip_bfloat16* __restrict__ A, const __hip_bfloat16* __restrict__ Bm,
             const float* __restrict__ bias, void* __restrict__ Cv,
             int M, int N, int K, int nnt, int ldc) {
  __shared__ __align__(16) char lds[131072];
  const int tid = threadIdx.x;
  const int w = tid >> 6, l = tid & 63;
  const int g = l >> 4, r = l & 15;
  const int wr = w >> 2, wc = w & 3;

  // bijective XCD swizzle (nwg % 8 == 0 for all our grids)
  const int nwg = gridDim.x;
  const int qq = nwg >> 3, r8 = nwg & 7;
  const int xcd = blockIdx.x & 7, idx = blockIdx.x >> 3;
  const int wgid = (xcd < r8 ? xcd * (qq + 1) : r8 * (qq + 1) + (xcd - r8) * qq) + idx;
  const int bn = (wgid % nnt) * 256, bm = (wgid / nnt) * 256;

  const int NKT = K >> 6;
  const size_t Kb2 = (size_t)K * 2;
  const int swz = (r & 7) << 4;

  auto issueHalf = [&](int kt, int h) {
    const char* src = (h < 2) ? (const char*)A : (const char*)Bm;
    const int rbase = (h < 2) ? bm : bn;
    char* reg = lds + (kt & 1) * 65536 + ((h < 2) ? 0 : 32768);
#pragma unroll
    for (int i = 0; i < 2; ++i) {
      const int lrow = (h & 1) * 128 + w * 16 + i * 8;   // wave-uniform dest row
      const int row = lrow + (l >> 3);                    // per-lane source row
      const int cb = (l & 7) * 16;
      gload_lds16(src + (size_t)(rbase + row) * Kb2 + (size_t)kt * 128 + (cb ^ ((row & 7) << 4)),
                  reg + lrow * 128);
    }
  };

  auto ldA = [&](int d, int mf, int kk) -> bf16x8 {
    const int row = wr * 128 + mf * 16 + r;
    return *(const bf16x8*)(lds + d * 65536 + row * 128 + ((kk * 64 + g * 16) ^ swz));
  };
  auto ldB = [&](int d, int nf, int kk) -> bf16x8 {
    const int row = wc * 64 + nf * 16 + r;
    return *(const bf16x8*)(lds + d * 65536 + 32768 + row * 128 + ((kk * 64 + g * 16) ^ swz));
  };

  f32x4 acc[8][4];
#pragma unroll
  for (int m = 0; m < 8; m++)
#pragma unroll
    for (int n = 0; n < 4; n++) acc[m][n] = (f32x4){0.f, 0.f, 0.f, 0.f};

#pragma unroll
  for (int h = 0; h < 4; ++h) issueHalf(0, h);
#pragma unroll
  for (int h = 0; h < 4; ++h) issueHalf(1, h);
  asm volatile("s_waitcnt vmcnt(8)" ::: "memory");
  BARRIER();

  bf16x8 af[4][2], bfr[4][2];

#pragma unroll 1
  for (int kt = 0; kt < NKT; ++kt) {
    const int d = kt & 1;

    if (kt >= 1 && kt + 1 < NKT) { issueHalf(kt + 1, 1); issueHalf(kt + 1, 3); }
#pragma unroll
    for (int mf = 0; mf < 4; mf++)
#pragma unroll
      for (int kk = 0; kk < 2; kk++) af[mf][kk] = ldA(d, mf, kk);
#pragma unroll
    for (int nf = 0; nf < 2; nf++)
#pragma unroll
      for (int kk = 0; kk < 2; kk++) bfr[nf][kk] = ldB(d, nf, kk);
    BARRIER();
    __builtin_amdgcn_s_setprio(1);
#pragma unroll
    for (int mf = 0; mf < 4; mf++)
#pragma unroll
      for (int nf = 0; nf < 2; nf++)
#pragma unroll
        for (int kk = 0; kk < 2; kk++)
          acc[mf][nf] = __builtin_amdgcn_mfma_f32_16x16x32_bf16(af[mf][kk], bfr[nf][kk], acc[mf][nf], 0, 0, 0);
    __builtin_amdgcn_s_setprio(0);
    BARRIER();

#pragma unroll
    for (int nf = 2; nf < 4; nf++)
#pragma unroll
      for (int kk = 0; kk < 2; kk++) bfr[nf][kk] = ldB(d, nf, kk);
    BARRIER();
    __builtin_amdgcn_s_setprio(1);
#pragma unroll
    for (int mf = 0; mf < 4; mf++)
#pragma unroll
      for (int nf = 2; nf < 4; nf++)
#pragma unroll
        for (int kk = 0; kk < 2; kk++)
          acc[mf][nf] = __builtin_amdgcn_mfma_f32_16x16x32_bf16(af[mf][kk], bfr[nf][kk], acc[mf][nf], 0, 0, 0);
    __builtin_amdgcn_s_setprio(0);
    BARRIER();

    if (kt + 2 < NKT) issueHalf(kt + 2, 2);
#pragma unroll
    for (int mf = 0; mf < 4; mf++)
#pragma unroll
      for (int kk = 0; kk < 2; kk++) af[mf][kk] = ldA(d, mf + 4, kk);
    BARRIER();
    __builtin_amdgcn_s_setprio(1);
#pragma unroll
    for (int mf = 0; mf < 4; mf++)
#pragma unroll
      for (int nf = 0; nf < 2; nf++)
#pragma unroll
        for (int kk = 0; kk < 2; kk++)
          acc[mf + 4][nf] = __builtin_amdgcn_mfma_f32_16x16x32_bf16(af[mf][kk], bfr[nf][kk], acc[mf + 4][nf], 0, 0, 0);
    __builtin_amdgcn_s_setprio(0);
    BARRIER();

    if (kt + 2 < NKT) {
      issueHalf(kt + 2, 0);
      asm volatile("s_waitcnt vmcnt(4)" ::: "memory");
    } else if (kt + 1 < NKT) {
      asm volatile("s_waitcnt vmcnt(0)" ::: "memory");
    }
    BARRIER();
    __builtin_amdgcn_s_setprio(1);
#pragma unroll
    for (int mf = 0; mf < 4; mf++)
#pragma unroll
      for (int nf = 2; nf < 4; nf++)
#pragma unroll
        for (int kk = 0; kk < 2; kk++)
          acc[mf + 4][nf] = __builtin_amdgcn_mfma_f32_16x16x32_bf16(af[mf][kk], bfr[nf][kk], acc[mf + 4][nf], 0, 0, 0);
    __builtin_amdgcn_s_setprio(0);
    BARRIER();
  }

#pragma unroll
  for (int nf = 0; nf < 4; nf++) {
    const int gcol = bn + wc * 64 + nf * 16 + r;
    const float bv = HAS_BIAS ? bias[gcol] : 0.f;
#pragma unroll
    for (int mf = 0; mf < 8; mf++) {
#pragma unroll
      for (int j = 0; j < 4; j++) {
        const int grow = bm + wr * 128 + mf * 16 + 4 * g + j;
        float v = acc[mf][nf][j] + bv;
        if constexpr (OUT_BF16)
          ((__hip_bfloat16*)Cv)[(size_t)grow * ldc + gcol] = __float2bfloat16(v);
        else
          ((float*)Cv)[(size_t)grow * ldc + gcol] = v;
      }
    }
  }
}

// ---------------- GEMM 128^2 (m97 structure) -------------------------------
template<bool HAS_BIAS, bool OUT_BF16>
__global__ __launch_bounds__(256)
void gemm_bt(const __hip_bfloat16* __restrict__ A, const __hip_bfloat16* __restrict__ Bm,
             const float* __restrict__ bias, void* __restrict__ Cv,
             int M, int N, int K, int ldc) {
  __shared__ __align__(16) __hip_bfloat16 As[128 * 32];
  __shared__ __align__(16) __hip_bfloat16 Bs[128 * 32];
  const int tid = threadIdx.x;
  const int w = tid >> 6, l = tid & 63;
  const int g = l >> 4, r = l & 15;
  const int wr = w >> 1, wc = w & 1;
  const int bm = blockIdx.x * 128;
  const int bn = blockIdx.y * 128;
  const int lr = l >> 2;
  const int lc = (l & 3) * 8;

  f32x4 acc[4][4];
#pragma unroll
  for (int m = 0; m < 4; m++)
#pragma unroll
    for (int n = 0; n < 4; n++) acc[m][n] = (f32x4){0.f, 0.f, 0.f, 0.f};

  for (int k0 = 0; k0 < K; k0 += 32) {
#pragma unroll
    for (int i = 0; i < 2; i++) {
      const int rb = w * 32 + i * 16;
      gload_lds16(&A[(size_t)(bm + rb + lr) * K + k0 + lc], &As[rb * 32]);
      gload_lds16(&Bm[(size_t)(bn + rb + lr) * K + k0 + lc], &Bs[rb * 32]);
    }
    __syncthreads();
    bf16x8 af[4], bfr[4];
#pragma unroll
    for (int m = 0; m < 4; m++) af[m] = *(const bf16x8*)&As[(wr * 64 + m * 16 + r) * 32 + g * 8];
#pragma unroll
    for (int n = 0; n < 4; n++) bfr[n] = *(const bf16x8*)&Bs[(wc * 64 + n * 16 + r) * 32 + g * 8];
#pragma unroll
    for (int m = 0; m < 4; m++)
#pragma unroll
      for (int n = 0; n < 4; n++)
        acc[m][n] = __builtin_amdgcn_mfma_f32_16x16x32_bf16(af[m], bfr[n], acc[m][n], 0, 0, 0);
    __syncthreads();
  }

#pragma unroll
  for (int m = 0; m < 4; m++) {
#pragma unroll
    for (int n = 0; n < 4; n++) {
      const int gcol = bn + wc * 64 + n * 16 + r;
      const float bv = HAS_BIAS ? bias[gcol] : 0.f;
#pragma unroll
      for (int j = 0; j < 4; j++) {
        const int grow = bm + wr * 64 + m * 16 + 4 * g + j;
        float v = acc[m][n][j] + bv;
        if constexpr (OUT_BF16)
          ((__hip_bfloat16*)Cv)[(size_t)grow * ldc + gcol] = __float2bfloat16(v);
        else
          ((float*)Cv)[(size_t)grow * ldc + gcol] = v;
      }
    }
  }
}

// ------ RoPE (Q scaled) + V transpose + Wo conversion, fused ---------------
// Blocks 0..8191: rope. 8192..8447: V transpose. 8448..20991: Wo cvt.
__global__ __launch_bounds__(256)
void rope_vt(__hip_bfloat16* __restrict__ QKV, const float* __restrict__ cosb,
             const float* __restrict__ sinb, __hip_bfloat16* __restrict__ Vt,
             const float* __restrict__ Wo, __hip_bfloat16* __restrict__ Wob) {
  if (blockIdx.x < 8192) {
    int i = blockIdx.x * 256 + threadIdx.x;
    int d = (i & 15) * 4;
    int hh = (i >> 4) & 31;
    int row = i >> 9;
    int cb = (hh < NHQ) ? hh * HD : HID + (hh - NHQ) * HD;
    const float qs = (hh < NHQ) ? 0.12751744055204955f : 1.0f;
    unsigned short* base = (unsigned short*)QKV + (size_t)row * NQKV + cb;
    float4 c = *(const float4*)&cosb[row * HD + d];
    float4 sn = *(const float4*)&sinb[row * HD + d];
    ushort4 u1 = *(const ushort4*)(base + d);
    ushort4 u2 = *(const ushort4*)(base + d + 64);
    float x1[4] = {bf2f(u1.x), bf2f(u1.y), bf2f(u1.z), bf2f(u1.w)};
    float x2[4] = {bf2f(u2.x), bf2f(u2.y), bf2f(u2.z), bf2f(u2.w)};
    float cc[4] = {c.x, c.y, c.z, c.w};
    float ss[4] = {sn.x, sn.y, sn.z, sn.w};
    ushort4 o1, o2;
    o1.x = f2bf((x1[0] * cc[0] - x2[0] * ss[0]) * qs); o2.x = f2bf((x2[0] * cc[0] + x1[0] * ss[0]) * qs);
    o1.y = f2bf((x1[1] * cc[1] - x2[1] * ss[1]) * qs); o2.y = f2bf((x2[1] * cc[1] + x1[1] * ss[1]) * qs);
    o1.z = f2bf((x1[2] * cc[2] - x2[2] * ss[2]) * qs); o2.z = f2bf((x2[2] * cc[2] + x1[2] * ss[2]) * qs);
    o1.w = f2bf((x1[3] * cc[3] - x2[3] * ss[3]) * qs); o2.w = f2bf((x2[3] * cc[3] + x1[3] * ss[3]) * qs);
    *(ushort4*)(base + d) = o1;
    *(ushort4*)(base + d + 64) = o2;
  } else if (blockIdx.x < 8448) {
    __shared__ ushort tile[64][136];
    const int bx = blockIdx.x - 8192;
    const int st = bx & 31, kv = (bx >> 5) & 3, b = bx >> 7;
    const int s0 = st * 64;
    const int t = threadIdx.x;
    const int sl = t >> 4, dv = (t & 15) * 8;
    const ushort* src = (const ushort*)QKV + (size_t)(b * SEQ) * NQKV + HID + 512 + kv * HD;
#pragma unroll
    for (int p = 0; p < 4; p++) {
      const int s = s0 + p * 16 + sl;
      *(uint4*)&tile[p * 16 + sl][dv] = *(const uint4*)&src[(size_t)s * NQKV + dv];
    }
    __syncthreads();
    ushort* dst = (ushort*)Vt + (size_t)((b * NKVH + kv) * HD) * SEQ;
#pragma unroll
    for (int it = 0; it < 8; it++) {
      const int idx = it * 256 + t;
      const int d = idx >> 4, sg = idx & 15;
      ushort4 o;
      o.x = tile[sg * 4 + 0][d];
      o.y = tile[sg * 4 + 1][d];
      o.z = tile[sg * 4 + 2][d];
      o.w = tile[sg * 4 + 3][d];
      *(ushort4*)&dst[(size_t)d * SEQ + s0 + sg * 4] = o;
    }
  } else {
    int off = (blockIdx.x - 8448) * 256 + threadIdx.x;   // < 3,211,264
    float4 v = ((const float4*)Wo)[off];
    ushort4 o;
    o.x = f2bf(v.x); o.y = f2bf(v.y); o.z = f2bf(v.z); o.w = f2bf(v.w);
    ((ushort4*)Wob)[off] = o;
  }
}

// ---------------- Flash attention (r18 structure, unchanged) ---------------
__global__ __launch_bounds__(256, 2)
void attn_fwd(const __hip_bfloat16* __restrict__ QKV, const __hip_bfloat16* __restrict__ Vt,
              __hip_bfloat16* __restrict__ AO) {
  const int head = blockIdx.x >> 1;
  const int b = blockIdx.x & 1;
  const int qb = 15 - blockIdx.y;           // LPT
  const int kvh = head / GRP;
  const int tid = threadIdx.x;
  const int w = tid >> 6, l = tid & 63;
  const int q32 = l & 31;
  const int hf = l >> 5;
  const int qw = qb * 128 + w * 32;
  const float NEGINF = -__builtin_inff();

  __shared__ __align__(16) __hip_bfloat16 Ks[2][64 * 128];
  __shared__ __align__(16) __hip_bfloat16 Vs[2][128 * 64];

  const char* Kb = (const char*)(QKV + (size_t)(b * SEQ) * NQKV + HID + kvh * HD);
  const char* Vb = (const char*)(Vt + (size_t)((b * NKVH + kvh) * HD) * SEQ);
  const __hip_bfloat16* Qb = QKV + (size_t)(b * SEQ + qw) * NQKV + head * HD;

  bf16x8 qf[8];
#pragma unroll
  for (int c = 0; c < 8; c++)
    qf[c] = *(const bf16x8*)&Qb[(size_t)q32 * NQKV + c * 16 + 8 * hf];

  f32x16 of[4] = {};
  float mrow = -3e38f, lsum = 0.f;   // half-partial lsum

  const int ntiles = 2 * qb + 2;

  auto stage = [&](int buf, int kv0) {
#pragma unroll
    for (int p = 0; p < 4; p++) {
      const int row = w * 16 + p * 4 + (l >> 4);
      const int cb = (l & 15) * 16;
      gload_lds16(Kb + (size_t)(kv0 + row) * (NQKV * 2) + (cb ^ ((row & 7) << 4)),
                  (char*)(Ks[buf]) + w * 4096 + p * 1024);
    }
#pragma unroll
    for (int p = 0; p < 4; p++) {
      const int row = w * 32 + p * 8 + (l >> 3);
      const int cb = (l & 7) * 16;
      gload_lds16(Vb + (size_t)row * (SEQ * 2) + (size_t)kv0 * 2 + (cb ^ ((row & 7) << 4)),
                  (char*)(Vs[buf]) + w * 4096 + p * 1024);
    }
  };

  stage(0, 0);
  __syncthreads();

  const int swz = (q32 & 7) << 4;
  const int qg = qw + q32;

  for (int t = 0; t < ntiles; t++) {
    const int cur = t & 1;
    if (t + 1 < ntiles) stage(cur ^ 1, t * 64 + 64);

#pragma unroll
    for (int half = 0; half < 2; half++) {
      const int kv0 = t * 64 + half * 32;
      if (kv0 <= qw + 31) {
        f32x16 s = {};
        const char* kb = (const char*)(Ks[cur]) + (half * 32 + q32) * 256;
        __builtin_amdgcn_s_setprio(1);
#pragma unroll
        for (int c = 0; c < 8; c++) {
          bf16x8 kf = *(const bf16x8*)(kb + ((c * 32 + 16 * hf) ^ swz));
          s = __builtin_amdgcn_mfma_f32_32x32x16_bf16(kf, qf[c], s, 0, 0, 0);
        }
        __builtin_amdgcn_s_setprio(0);

        float pmax = -3e38f;
        if (kv0 + 31 <= qw) {
#pragma unroll
          for (int j = 0; j < 16; j++) pmax = fmaxf(pmax, s[j]);
        } else {
#pragma unroll
          for (int j = 0; j < 16; j++) {
            const int kvl = (j & 3) + 8 * (j >> 2) + 4 * hf;
            s[j] = (kv0 + kvl <= qg) ? s[j] : NEGINF;
            pmax = fmaxf(pmax, s[j]);
          }
        }
        pmax = fmaxf(pmax, __shfl_xor(pmax, 32));

        float rs = 0.f;
        if (__all(pmax - mrow <= 11.5f)) {
#pragma unroll
          for (int j = 0; j < 16; j++) { float p = exp2f(s[j] - mrow); s[j] = p; rs += p; }
        } else {
          const float nm = fmaxf(mrow, pmax);
          const float al = exp2f(mrow - nm);
          mrow = nm;
#pragma unroll
          for (int j = 0; j < 16; j++) { float p = exp2f(s[j] - nm); s[j] = p; rs += p; }
          lsum *= al;
#pragma unroll
          for (int db = 0; db < 4; db++) of[db] *= al;
        }
        lsum += rs;

        int wv[8];
#pragma unroll
        for (int k = 0; k < 8; k++)
          wv[k] = (int)((unsigned)f2bf(s[2 * k]) | ((unsigned)f2bf(s[2 * k + 1]) << 16));

        {
          auto ra = __builtin_amdgcn_permlane32_swap(wv[0], wv[2], false, false);
          auto rb = __builtin_amdgcn_permlane32_swap(wv[1], wv[3], false, false);
          union { int4v i; bf16x8 h; } u;
          u.i = (int4v){(int)ra[0], (int)rb[0], (int)ra[1], (int)rb[1]};
          const bf16x8 pB = u.h;
          __builtin_amdgcn_s_setprio(1);
#pragma unroll
          for (int db = 0; db < 4; db++) {
            const char* vp = (const char*)(Vs[cur]) + (db * 32 + q32) * 128;
            bf16x8 vf = *(const bf16x8*)(vp + ((half * 64 + 0 + 16 * hf) ^ swz));
            of[db] = __builtin_amdgcn_mfma_f32_32x32x16_bf16(vf, pB, of[db], 0, 0, 0);
          }
          __builtin_amdgcn_s_setprio(0);
        }
        {
          auto rc = __builtin_amdgcn_permlane32_swap(wv[4], wv[6], false, false);
          auto rd = __builtin_amdgcn_permlane32_swap(wv[5], wv[7], false, false);
          union { int4v i; bf16x8 h; } u2;
          u2.i = (int4v){(int)rc[0], (int)rd[0], (int)rc[1], (int)rd[1]};
          const bf16x8 pB = u2.h;
          __builtin_amdgcn_s_setprio(1);
#pragma unroll
          for (int db = 0; db < 4; db++) {
            const char* vp = (const char*)(Vs[cur]) + (db * 32 + q32) * 128;
            bf16x8 vf = *(const bf16x8*)(vp + ((half * 64 + 32 + 16 * hf) ^ swz));
            of[db] = __builtin_amdgcn_mfma_f32_32x32x16_bf16(vf, pB, of[db], 0, 0, 0);
          }
          __builtin_amdgcn_s_setprio(0);
        }
      }
    }
    if (t + 1 < ntiles) __syncthreads();
  }

  const float ltot = lsum + __shfl_xor(lsum, 32);
  unsigned short* AOu = (unsigned short*)AO;
  const float inv = 1.0f / ltot;
  const size_t rowb = (size_t)(b * SEQ + qw + q32) * HID + head * HD;
#pragma unroll
  for (int db = 0; db < 4; db++) {
#pragma unroll
    for (int qd = 0; qd < 4; qd++) {
      ushort4 o;
      o.x = f2bf(of[db][4 * qd + 0] * inv);
      o.y = f2bf(of[db][4 * qd + 1] * inv);
      o.z = f2bf(of[db][4 * qd + 2] * inv);
      o.w = f2bf(of[db][4 * qd + 3] * inv);
      *(ushort4*)&AOu[rowb + db * 32 + 8 * qd + 4 * hf] = o;
    }
  }
}

// ---------------------------------------------------------------------------
extern "C" void kernel_launch(void* const* d_in, const int* in_sizes, int n_in,
                              void* d_out, int out_size, void* d_ws, size_t ws_size,
                              hipStream_t stream) {
  const float* hs = (const float*)d_in[0];
  const float* cosb = (const float*)d_in[1];
  const float* sinb = (const float*)d_in[2];
  const float* Wq = (const float*)d_in[3];
  const float* bq = (const float*)d_in[4];
  const float* Wk = (const float*)d_in[5];
  const float* bk = (const float*)d_in[6];
  const float* Wv = (const float*)d_in[7];
  const float* bv = (const float*)d_in[8];
  const float* Wo = (const float*)d_in[9];

  char* ws = (char*)d_ws;
  __hip_bfloat16* Xb = (__hip_bfloat16*)(ws);
  __hip_bfloat16* Wcat = (__hip_bfloat16*)(ws + 29360128);
  float* bcat = (float*)(ws + 62390272);
  __hip_bfloat16* QKVb = (__hip_bfloat16*)(ws + 62408704);
  __hip_bfloat16* Vt = (__hip_bfloat16*)(ws + 100157440);
  __hip_bfloat16* AOb = Xb;    // X dead after projections
  __hip_bfloat16* Wob = Wcat;  // Wq/Wk rows dead after QK GEMM

  // Fused conversions (X, Wq, Wk, Wv) + bias concat (tail blocks)
  cvt_fused<<<30482, 256, 0, stream>>>(hs, Wq, Wk, Wv, bq, bk, bv, Xb, Wcat, bcat);

  // QK projection: [4096 x 4096] -> QKVb cols 0..4095. 256 blocks = 1 round.
  gemm256<true, true><<<256, 512, 0, stream>>>(Xb, Wcat, bcat, QKVb,
                                               4096, 4096, HID, 16, NQKV);

  // V projection: [4096 x 512] on 128^2 tiles -> 128 blocks.
  dim3 gv(32, 4);
  gemm_bt<true, true><<<gv, 256, 0, stream>>>(Xb, Wcat + (size_t)4096 * 3584,
                                              bcat + 4096, QKVb + 4096,
                                              4096, 512, HID, NQKV);

  // RoPE (Q pre-scaled) + V transpose + Wo conversion, one launch
  rope_vt<<<20992, 256, 0, stream>>>(QKVb, cosb, sinb, Vt, Wo, Wob);

  // Flash attention
  dim3 ga(56, 16);
  attn_fwd<<<ga, 256, 0, stream>>>(QKVb, Vt, AOb);

  // O projection -> f32 out (224 blocks; nnt=14 -> whole-m-row XCD chunks)
  gemm256<false, false><<<224, 512, 0, stream>>>(AOb, Wob, nullptr, d_out,
                                                 4096, HID, HID, 14, HID);
}